// Round 1
// baseline (20559.944 us; speedup 1.0000x reference)
//
#include <hip/hip_runtime.h>
#include <hip/hip_bf16.h>

// Problem constants
#define B 128
#define S 196
#define E 2048
#define D 512
#define A 256
#define V 10000
#define EM 512
#define T 20

// ---------------------------------------------------------------------------
// Generic fp32 tiled GEMM: C[M,N] = sum_p A_p[M,K_p] @ W_p[K_p,N] (+bias1+bias2)
// 64x64 block tile, BK=16, 256 threads, 4x4 per thread.
// ---------------------------------------------------------------------------
struct Pair {
    const float* Aptr;
    int lda;
    const float* Wptr;
    int ldw;
    int K;
};

template <int NP>
__global__ __launch_bounds__(256) void gemm_f32(
    int M, int N, Pair p0, Pair p1, Pair p2,
    const float* __restrict__ bias1, const float* __restrict__ bias2,
    float* __restrict__ C, long ldc)
{
    __shared__ float As[64][17];     // [m][k], padded to dodge bank conflicts
    __shared__ float Ws[16][64];     // [k][n]

    const int tid  = threadIdx.x;
    const int row0 = blockIdx.y * 64;
    const int col0 = blockIdx.x * 64;
    const int tx   = tid & 15;       // output col group
    const int ty   = tid >> 4;       // output row group

    float acc[4][4] = {};

    Pair ps[3] = {p0, p1, p2};
#pragma unroll
    for (int p = 0; p < NP; ++p) {
        const float* Ag = ps[p].Aptr;
        const float* Wg = ps[p].Wptr;
        const int lda = ps[p].lda;
        const int ldw = ps[p].ldw;
        const int K   = ps[p].K;     // must be multiple of 16 (true for all uses)

        for (int k0 = 0; k0 < K; k0 += 16) {
            // load A tile 64(m) x 16(k)
            {
                const int k  = tid & 15;
                const int mb = tid >> 4;
#pragma unroll
                for (int i = 0; i < 4; ++i) {
                    const int m  = mb + 16 * i;
                    const int gr = row0 + m;
                    float v = 0.0f;
                    if (gr < M) v = Ag[(size_t)gr * lda + k0 + k];
                    As[m][k] = v;
                }
            }
            // load W tile 16(k) x 64(n)
            {
                const int n  = tid & 63;
                const int kb = tid >> 6;
                const int gc = col0 + n;
#pragma unroll
                for (int i = 0; i < 4; ++i) {
                    const int k = kb * 4 + i;
                    float v = 0.0f;
                    if (gc < N) v = Wg[(size_t)(k0 + k) * ldw + gc];
                    Ws[k][n] = v;
                }
            }
            __syncthreads();

#pragma unroll
            for (int k = 0; k < 16; ++k) {
                float av[4];
#pragma unroll
                for (int i = 0; i < 4; ++i) av[i] = As[ty * 4 + i][k];
                const float4 bv = reinterpret_cast<const float4*>(&Ws[k][0])[tx];
                const float bvv[4] = {bv.x, bv.y, bv.z, bv.w};
#pragma unroll
                for (int i = 0; i < 4; ++i)
#pragma unroll
                    for (int j = 0; j < 4; ++j)
                        acc[i][j] += av[i] * bvv[j];
            }
            __syncthreads();
        }
    }

    // epilogue
#pragma unroll
    for (int i = 0; i < 4; ++i) {
        const int r = row0 + ty * 4 + i;
        if (r >= M) continue;
#pragma unroll
        for (int j = 0; j < 4; ++j) {
            const int cidx = col0 + tx * 4 + j;
            if (cidx >= N) continue;
            float v = acc[i][j];
            if (bias1) v += bias1[cidx];
            if (bias2) v += bias2[cidx];
            C[(size_t)r * ldc + cidx] = v;
        }
    }
}

// ---------------------------------------------------------------------------
// mean over S: F[B,S,E] -> mean[B,E]
// ---------------------------------------------------------------------------
__global__ __launch_bounds__(256) void mean_pool(const float* __restrict__ F,
                                                 float* __restrict__ mean)
{
    const int idx = blockIdx.x * 256 + threadIdx.x;   // B*E
    const int b = idx >> 11;                           // /E
    const int e = idx & (E - 1);
    const float* Fb = F + (size_t)b * S * E + e;
    float acc = 0.0f;
    for (int s = 0; s < S; ++s) acc += Fb[(size_t)s * E];
    mean[idx] = acc * (1.0f / (float)S);
}

// ---------------------------------------------------------------------------
// embedding gather: embs[B,T,EM] = table[captions[B,T]]
// one float4 per thread
// ---------------------------------------------------------------------------
__global__ __launch_bounds__(256) void gather_embs(const int* __restrict__ captions,
                                                   const float* __restrict__ table,
                                                   float* __restrict__ out)
{
    const int idx = blockIdx.x * 256 + threadIdx.x;   // B*T*(EM/4)
    const int per_row = EM / 4;                        // 128
    const int row = idx / per_row;                     // b*T + t
    const int col = idx - row * per_row;
    const int cap = captions[row];
    reinterpret_cast<float4*>(out)[idx] =
        reinterpret_cast<const float4*>(table + (size_t)cap * EM)[col];
}

// ---------------------------------------------------------------------------
// fused attention scores + softmax.  grid = B blocks, 256 threads.
// scores[b,s] = sum_a relu(enc_att[b,s,a] + dec_att[b,a]) * W_fa[a] + b_fa
// alpha = softmax_s(scores)
// ---------------------------------------------------------------------------
__global__ __launch_bounds__(256) void attn_softmax(
    const float* __restrict__ enc_att,   // [B,S,A]
    const float* __restrict__ dec_att,   // [B,A]
    const float* __restrict__ W_fa,      // [A]
    const float* __restrict__ b_fa,      // [1]
    float* __restrict__ alpha)           // [B,S]
{
    const int b   = blockIdx.x;
    const int tid = threadIdx.x;
    const int wave = tid >> 6;
    const int lane = tid & 63;

    __shared__ float dec[A];
    __shared__ float wfa[A];
    __shared__ float sc[S];
    __shared__ float redm[4];
    __shared__ float reds[4];

    dec[tid] = dec_att[b * A + tid];     // blockDim == A == 256
    wfa[tid] = W_fa[tid];
    __syncthreads();

    for (int s = wave; s < S; s += 4) {
        const float* ea = enc_att + ((size_t)b * S + s) * A;
        float v = 0.0f;
#pragma unroll
        for (int i = 0; i < 4; ++i) {
            const int a = lane + 64 * i;
            float x = ea[a] + dec[a];
            x = x > 0.0f ? x : 0.0f;
            v += x * wfa[a];
        }
        for (int off = 32; off; off >>= 1) v += __shfl_down(v, off);
        if (lane == 0) sc[s] = v + b_fa[0];
    }
    __syncthreads();

    // block max
    float m = -1e30f;
    for (int s = tid; s < S; s += 256) m = fmaxf(m, sc[s]);
    for (int off = 32; off; off >>= 1) m = fmaxf(m, __shfl_down(m, off));
    if (lane == 0) redm[wave] = m;
    __syncthreads();
    if (tid == 0)
        redm[0] = fmaxf(fmaxf(redm[0], redm[1]), fmaxf(redm[2], redm[3]));
    __syncthreads();
    m = redm[0];

    // exp + sum
    float sum = 0.0f;
    for (int s = tid; s < S; s += 256) {
        const float ev = expf(sc[s] - m);
        sc[s] = ev;
        sum += ev;
    }
    for (int off = 32; off; off >>= 1) sum += __shfl_down(sum, off);
    if (lane == 0) reds[wave] = sum;
    __syncthreads();
    if (tid == 0) reds[0] = reds[0] + reds[1] + reds[2] + reds[3];
    __syncthreads();
    const float inv = 1.0f / reds[0];

    for (int s = tid; s < S; s += 256) alpha[b * S + s] = sc[s] * inv;
}

// ---------------------------------------------------------------------------
// context[b,e] = sum_s alpha[b,s] * F[b,s,e].  grid = B*(E/256), 256 threads.
// ---------------------------------------------------------------------------
__global__ __launch_bounds__(256) void context_kernel(
    const float* __restrict__ F,
    const float* __restrict__ alpha,
    float* __restrict__ ctx)
{
    const int chunks = E / 256;                     // 8
    const int b = blockIdx.x / chunks;
    const int ec = blockIdx.x - b * chunks;
    const int e = ec * 256 + threadIdx.x;

    __shared__ float al[S];
    for (int s = threadIdx.x; s < S; s += 256) al[s] = alpha[b * S + s];
    __syncthreads();

    const float* Fb = F + (size_t)b * S * E + e;
    float acc = 0.0f;
    for (int s = 0; s < S; ++s) acc += al[s] * Fb[(size_t)s * E];
    ctx[b * E + e] = acc;
}

// ---------------------------------------------------------------------------
// LSTM cell pointwise. gates[B,4D] (i,f,g,o). updates h,c in place.
// ---------------------------------------------------------------------------
__global__ __launch_bounds__(256) void lstm_cell(
    const float* __restrict__ gates,
    float* __restrict__ h,
    float* __restrict__ c)
{
    const int idx = blockIdx.x * 256 + threadIdx.x;  // B*D
    const int b = idx >> 9;                          // /D
    const int d = idx & (D - 1);
    const float* g = gates + (size_t)b * 4 * D;
    const float gi = g[d];
    const float gf = g[D + d];
    const float gg = g[2 * D + d];
    const float go = g[3 * D + d];
    const float si = 1.0f / (1.0f + expf(-gi));
    const float sf = 1.0f / (1.0f + expf(-gf));
    const float so = 1.0f / (1.0f + expf(-go));
    const float cn = sf * c[idx] + si * tanhf(gg);
    c[idx] = cn;
    h[idx] = so * tanhf(cn);
}

// ---------------------------------------------------------------------------
// launch
// ---------------------------------------------------------------------------
extern "C" void kernel_launch(void* const* d_in, const int* in_sizes, int n_in,
                              void* d_out, int out_size, void* d_ws, size_t ws_size,
                              hipStream_t stream)
{
    const float* F        = (const float*)d_in[0];
    const int*   captions = (const int*)  d_in[1];
    const float* table    = (const float*)d_in[2];
    const float* W_ea     = (const float*)d_in[3];
    const float* b_ea     = (const float*)d_in[4];
    const float* W_da     = (const float*)d_in[5];
    const float* b_da     = (const float*)d_in[6];
    const float* W_fa     = (const float*)d_in[7];
    const float* b_fa     = (const float*)d_in[8];
    const float* W_ih     = (const float*)d_in[9];
    const float* b_ih     = (const float*)d_in[10];
    const float* W_hh     = (const float*)d_in[11];
    const float* b_hh     = (const float*)d_in[12];
    const float* W_cp     = (const float*)d_in[13];
    const float* b_cp     = (const float*)d_in[14];
    const float* W_hp     = (const float*)d_in[15];
    const float* b_hp     = (const float*)d_in[16];
    const float* W_op     = (const float*)d_in[17];
    const float* b_op     = (const float*)d_in[18];
    const float* W_inith  = (const float*)d_in[19];
    const float* b_inith  = (const float*)d_in[20];
    const float* W_initc  = (const float*)d_in[21];
    const float* b_initc  = (const float*)d_in[22];

    float* out = (float*)d_out;

    // workspace layout (floats)
    float* ws = (float*)d_ws;
    float* mean_feat = ws;                 ws += B * E;        // 262144
    float* h         = ws;                 ws += B * D;        // 65536
    float* c         = ws;                 ws += B * D;        // 65536
    float* enc_att   = ws;                 ws += (size_t)B * S * A;  // 6422528
    float* embs      = ws;                 ws += (size_t)B * T * EM; // 1310720
    float* dec_att   = ws;                 ws += B * A;        // 32768
    float* alpha     = ws;                 ws += B * S;        // 25088
    float* ctx       = ws;                 ws += B * E;        // 262144
    float* gates     = ws;                 ws += B * 4 * D;    // 262144
    float* feat      = ws;                 ws += B * EM;       // 65536

    const Pair ZP = {nullptr, 0, nullptr, 0, 0};

    // ---- setup phase ----
    mean_pool<<<(B * E) / 256, 256, 0, stream>>>(F, mean_feat);

    // h0 = mean @ W_inith + b ; c0 = mean @ W_initc + b
    {
        Pair p = {mean_feat, E, W_inith, D, E};
        gemm_f32<1><<<dim3(D / 64, B / 64), 256, 0, stream>>>(
            B, D, p, ZP, ZP, b_inith, nullptr, h, D);
    }
    {
        Pair p = {mean_feat, E, W_initc, D, E};
        gemm_f32<1><<<dim3(D / 64, B / 64), 256, 0, stream>>>(
            B, D, p, ZP, ZP, b_initc, nullptr, c, D);
    }

    // enc_att = F @ W_ea + b_ea   (M = B*S)
    {
        Pair p = {F, E, W_ea, A, E};
        gemm_f32<1><<<dim3(A / 64, (B * S) / 64), 256, 0, stream>>>(
            B * S, A, p, ZP, ZP, b_ea, nullptr, enc_att, A);
    }

    gather_embs<<<(B * T * (EM / 4)) / 256, 256, 0, stream>>>(captions, table, embs);

    // ---- per-step loop ----
    for (int t = 0; t < T; ++t) {
        // dec_att = h @ W_da + b_da
        {
            Pair p = {h, D, W_da, A, D};
            gemm_f32<1><<<dim3(A / 64, B / 64), 256, 0, stream>>>(
                B, A, p, ZP, ZP, b_da, nullptr, dec_att, A);
        }

        attn_softmax<<<B, 256, 0, stream>>>(enc_att, dec_att, W_fa, b_fa, alpha);

        context_kernel<<<B * (E / 256), 256, 0, stream>>>(F, alpha, ctx);

        // gates = emb_t @ W_ih[0:EM] + ctx @ W_ih[EM:] + h @ W_hh + b_ih + b_hh
        {
            Pair p0 = {embs + (size_t)t * EM, T * EM, W_ih, 4 * D, EM};
            Pair p1 = {ctx, E, W_ih + (size_t)EM * 4 * D, 4 * D, E};
            Pair p2 = {h, D, W_hh, 4 * D, D};
            gemm_f32<3><<<dim3((4 * D) / 64, B / 64), 256, 0, stream>>>(
                B, 4 * D, p0, p1, p2, b_ih, b_hh, gates, 4 * D);
        }

        lstm_cell<<<(B * D) / 256, 256, 0, stream>>>(gates, h, c);

        // feat = ctx @ W_cp + h_new @ W_hp + b_cp + b_hp
        {
            Pair p0 = {ctx, E, W_cp, EM, E};
            Pair p1 = {h, D, W_hp, EM, D};
            gemm_f32<2><<<dim3(EM / 64, B / 64), 256, 0, stream>>>(
                B, EM, p0, p1, ZP, b_cp, b_hp, feat, EM);
        }

        // logits -> out[:, t, :]
        {
            Pair p = {feat, EM, W_op, V, EM};
            gemm_f32<1><<<dim3((V + 63) / 64, B / 64), 256, 0, stream>>>(
                B, V, p, ZP, ZP, b_op, nullptr, out + (size_t)t * V, (long)T * V);
        }
    }
}

// Round 2
// 5063.107 us; speedup vs baseline: 4.0607x; 4.0607x over previous
//
#include <hip/hip_runtime.h>
#include <hip/hip_bf16.h>

// Problem constants
#define B 128
#define S 196
#define E 2048
#define D 512
#define A 256
#define V 10000
#define EM 512
#define T 20

typedef unsigned short u16;
typedef __bf16 bf16x8 __attribute__((ext_vector_type(8)));
typedef float f32x4 __attribute__((ext_vector_type(4)));
typedef u16 u16x8 __attribute__((ext_vector_type(8)));
typedef u16 u16x4 __attribute__((ext_vector_type(4)));

__device__ inline u16 f2bf(float f) {
    union { float f; unsigned u; } x; x.f = f;
    return (u16)((x.u + 0x7FFFu + ((x.u >> 16) & 1u)) >> 16);
}
__device__ inline float bf2f(u16 h) {
    union { unsigned u; float f; } x; x.u = ((unsigned)h) << 16;
    return x.f;
}
__device__ inline bf16x8 ld_bf8(const u16* p) {
    return __builtin_bit_cast(bf16x8, *reinterpret_cast<const u16x8*>(p));
}
__device__ inline bf16x8 cvt_bf8(const float* p) {
    float4 u = *reinterpret_cast<const float4*>(p);
    float4 v = *reinterpret_cast<const float4*>(p + 4);
    u16x8 t;
    t[0] = f2bf(u.x); t[1] = f2bf(u.y); t[2] = f2bf(u.z); t[3] = f2bf(u.w);
    t[4] = f2bf(v.x); t[5] = f2bf(v.y); t[6] = f2bf(v.z); t[7] = f2bf(v.w);
    return __builtin_bit_cast(bf16x8, t);
}

// ===========================================================================
// MFMA bf16 GEMM, no LDS: stream A ([M][K] bf16 or fp32) and B^T ([Npad][K]
// bf16) fragments directly from global. Block = 4 waves; wave tile 32M x 64N.
// WM x WN = 4 wave arrangement. grid = (ceil(N/(WN*64)), M/(WM*32)).
// Fused sum of up to 3 A@B pairs + up to 2 biases. OutT = float or u16(bf16).
// ===========================================================================
struct PairT {
    const void* Ap;  // bf16 (u16*) or float* when AF32
    long lda;        // elements
    const u16* Bt;   // B^T [Npad][K] bf16
    long ldb;
    int K;           // multiple of 32
};

template <int NP, bool AF32, typename OutT, int WM, int WN>
__global__ __launch_bounds__(256) void gemm_mfma(
    int N, PairT q0, PairT q1, PairT q2,
    const float* __restrict__ bias1, const float* __restrict__ bias2,
    OutT* __restrict__ Cc, long ldc)
{
    const int tid  = threadIdx.x;
    const int w    = tid >> 6;
    const int lane = tid & 63;
    const int lr   = lane & 15;   // A-row / B-col / C-col index within frag
    const int lg   = lane >> 4;   // k-group
    const int mrow = blockIdx.y * (WM * 32) + (w / WN) * 32;
    const int ncol = blockIdx.x * (WN * 64) + (w % WN) * 64;

    f32x4 acc[2][4];
#pragma unroll
    for (int i = 0; i < 2; ++i)
#pragma unroll
        for (int j = 0; j < 4; ++j) acc[i][j] = (f32x4){0.f, 0.f, 0.f, 0.f};

    const PairT qs[3] = {q0, q1, q2};
#pragma unroll
    for (int p = 0; p < NP; ++p) {
        const PairT pp = qs[p];
        const int nk = pp.K >> 5;
        const u16*   Ab = (const u16*)pp.Ap;
        const float* Af = (const float*)pp.Ap;
        const size_t a0off = (size_t)(mrow + lr) * pp.lda + lg * 8;
        const size_t a1off = a0off + (size_t)16 * pp.lda;
        const u16* Bp = pp.Bt + (size_t)(ncol + lr) * pp.ldb + lg * 8;
        const size_t bstep = (size_t)16 * pp.ldb;

#pragma unroll 2
        for (int kk = 0; kk < nk; ++kk) {
            const int ko = kk * 32;
            bf16x8 a0, a1;
            if (AF32) {
                a0 = cvt_bf8(Af + a0off + ko);
                a1 = cvt_bf8(Af + a1off + ko);
            } else {
                a0 = ld_bf8(Ab + a0off + ko);
                a1 = ld_bf8(Ab + a1off + ko);
            }
            const bf16x8 bb0 = ld_bf8(Bp + ko);
            const bf16x8 bb1 = ld_bf8(Bp + ko + bstep);
            const bf16x8 bb2 = ld_bf8(Bp + ko + 2 * bstep);
            const bf16x8 bb3 = ld_bf8(Bp + ko + 3 * bstep);
            acc[0][0] = __builtin_amdgcn_mfma_f32_16x16x32_bf16(a0, bb0, acc[0][0], 0, 0, 0);
            acc[1][0] = __builtin_amdgcn_mfma_f32_16x16x32_bf16(a1, bb0, acc[1][0], 0, 0, 0);
            acc[0][1] = __builtin_amdgcn_mfma_f32_16x16x32_bf16(a0, bb1, acc[0][1], 0, 0, 0);
            acc[1][1] = __builtin_amdgcn_mfma_f32_16x16x32_bf16(a1, bb1, acc[1][1], 0, 0, 0);
            acc[0][2] = __builtin_amdgcn_mfma_f32_16x16x32_bf16(a0, bb2, acc[0][2], 0, 0, 0);
            acc[1][2] = __builtin_amdgcn_mfma_f32_16x16x32_bf16(a1, bb2, acc[1][2], 0, 0, 0);
            acc[0][3] = __builtin_amdgcn_mfma_f32_16x16x32_bf16(a0, bb3, acc[0][3], 0, 0, 0);
            acc[1][3] = __builtin_amdgcn_mfma_f32_16x16x32_bf16(a1, bb3, acc[1][3], 0, 0, 0);
        }
    }

#pragma unroll
    for (int ni = 0; ni < 4; ++ni) {
        const int col = ncol + ni * 16 + lr;
        if (col >= N) continue;
        float bs = 0.f;
        if (bias1) bs += bias1[col];
        if (bias2) bs += bias2[col];
#pragma unroll
        for (int mi = 0; mi < 2; ++mi) {
#pragma unroll
            for (int r = 0; r < 4; ++r) {
                const int row = mrow + mi * 16 + lg * 4 + r;
                const float v = acc[mi][ni][r] + bs;
                if constexpr (sizeof(OutT) == 2)
                    Cc[(size_t)row * ldc + col] = (OutT)f2bf(v);
                else
                    Cc[(size_t)row * ldc + col] = v;
            }
        }
    }
}

// ===========================================================================
// transpose fp32 [K][N] -> bf16 [Npad][K]; pad rows (n>=N) are zeroed.
// grid = (Npad/32, K/32), 256 threads.
// ===========================================================================
__global__ __launch_bounds__(256) void transpose_bf(
    const float* __restrict__ in, int K, int N, u16* __restrict__ out)
{
    __shared__ float t[32][33];
    const int k0 = blockIdx.y * 32, n0 = blockIdx.x * 32;
    const int c = threadIdx.x & 31, r8 = threadIdx.x >> 5;
#pragma unroll
    for (int i = 0; i < 4; ++i) {
        const int k = r8 + i * 8;
        float v = 0.f;
        if (n0 + c < N) v = in[(size_t)(k0 + k) * N + n0 + c];
        t[k][c] = v;
    }
    __syncthreads();
#pragma unroll
    for (int i = 0; i < 4; ++i) {
        const int n = r8 + i * 8;
        out[(size_t)(n0 + n) * K + k0 + c] = f2bf(t[c][n]);
    }
}

// ===========================================================================
// fused: mean over S (fp32 acc -> bf16) and optional F -> bf16 copy
// ===========================================================================
template <bool WRITE>
__global__ __launch_bounds__(256) void conv_mean(
    const float* __restrict__ F, u16* __restrict__ Fbf, u16* __restrict__ meanbf)
{
    const int idx = blockIdx.x * 256 + threadIdx.x;  // over B*E
    const int b = idx >> 11;
    const int e = idx & (E - 1);
    const float* src = F + (size_t)b * S * E + e;
    float acc = 0.f;
    for (int s = 0; s < S; ++s) {
        const float v = src[(size_t)s * E];
        acc += v;
        if (WRITE) Fbf[(size_t)b * S * E + (size_t)s * E + e] = f2bf(v);
    }
    meanbf[idx] = f2bf(acc * (1.f / (float)S));
}

// ===========================================================================
// embedding gather -> bf16 embs [B][T][EM]
// ===========================================================================
__global__ __launch_bounds__(256) void gather_embs_bf(
    const int* __restrict__ captions, const float* __restrict__ table,
    u16* __restrict__ out)
{
    const int idx = blockIdx.x * 256 + threadIdx.x;  // B*T*(EM/8)
    const int row = idx >> 6;                        // b*T + t
    const int ch  = idx & 63;
    const int cap = captions[row];
    const float* src = table + (size_t)cap * EM + ch * 8;
    float4 u = *reinterpret_cast<const float4*>(src);
    float4 v = *reinterpret_cast<const float4*>(src + 4);
    u16x8 t;
    t[0] = f2bf(u.x); t[1] = f2bf(u.y); t[2] = f2bf(u.z); t[3] = f2bf(u.w);
    t[4] = f2bf(v.x); t[5] = f2bf(v.y); t[6] = f2bf(v.z); t[7] = f2bf(v.w);
    *reinterpret_cast<u16x8*>(out + (size_t)row * EM + ch * 8) = t;
}

// ===========================================================================
// fused attention scores + softmax; enc_att bf16. grid = B, 256 threads.
// ===========================================================================
__global__ __launch_bounds__(256) void attn_softmax_bf(
    const u16* __restrict__ enc, const float* __restrict__ dec_att,
    const float* __restrict__ W_fa, const float* __restrict__ b_fa,
    float* __restrict__ alpha)
{
    const int b = blockIdx.x, tid = threadIdx.x;
    const int wave = tid >> 6, lane = tid & 63;

    __shared__ float dec[A], wfa[A], sc[S], redm[4], reds[4];
    dec[tid] = dec_att[b * A + tid];
    wfa[tid] = W_fa[tid];
    __syncthreads();

    for (int s = wave; s < S; s += 4) {
        const u16* ea = enc + ((size_t)b * S + s) * A + lane * 4;
        const u16x4 v = *reinterpret_cast<const u16x4*>(ea);
        float acc = 0.f;
#pragma unroll
        for (int j = 0; j < 4; ++j) {
            float x = bf2f(v[j]) + dec[lane * 4 + j];
            x = x > 0.f ? x : 0.f;
            acc += x * wfa[lane * 4 + j];
        }
        for (int off = 32; off; off >>= 1) acc += __shfl_down(acc, off);
        if (lane == 0) sc[s] = acc + b_fa[0];
    }
    __syncthreads();

    float m = -1e30f;
    for (int s = tid; s < S; s += 256) m = fmaxf(m, sc[s]);
    for (int off = 32; off; off >>= 1) m = fmaxf(m, __shfl_down(m, off));
    if (lane == 0) redm[wave] = m;
    __syncthreads();
    if (tid == 0) redm[0] = fmaxf(fmaxf(redm[0], redm[1]), fmaxf(redm[2], redm[3]));
    __syncthreads();
    m = redm[0];

    float sum = 0.f;
    for (int s = tid; s < S; s += 256) {
        const float ev = expf(sc[s] - m);
        sc[s] = ev;
        sum += ev;
    }
    for (int off = 32; off; off >>= 1) sum += __shfl_down(sum, off);
    if (lane == 0) reds[wave] = sum;
    __syncthreads();
    if (tid == 0) reds[0] = reds[0] + reds[1] + reds[2] + reds[3];
    __syncthreads();
    const float inv = 1.f / reds[0];
    for (int s = tid; s < S; s += 256) alpha[b * S + s] = sc[s] * inv;
}

// ===========================================================================
// context[b,:] = alpha[b,:] @ F[b]  -> bf16 ctx. grid = B, 256 thr, 8 e/thr.
// ===========================================================================
template <bool FBF>
__global__ __launch_bounds__(256) void context_k(
    const void* __restrict__ Fv, const float* __restrict__ alpha,
    u16* __restrict__ ctx)
{
    const int b = blockIdx.x;
    const int e0 = threadIdx.x * 8;
    __shared__ float al[S];
    for (int s = threadIdx.x; s < S; s += 256) al[s] = alpha[b * S + s];
    __syncthreads();

    float acc[8] = {0.f, 0.f, 0.f, 0.f, 0.f, 0.f, 0.f, 0.f};
    if (FBF) {
        const u16* Fb = (const u16*)Fv + (size_t)b * S * E + e0;
        for (int s = 0; s < S; ++s) {
            const u16x8 v = *reinterpret_cast<const u16x8*>(Fb + (size_t)s * E);
            const float a = al[s];
#pragma unroll
            for (int j = 0; j < 8; ++j) acc[j] += a * bf2f(v[j]);
        }
    } else {
        const float* Ff = (const float*)Fv + (size_t)b * S * E + e0;
        for (int s = 0; s < S; ++s) {
            const float4 u = *reinterpret_cast<const float4*>(Ff + (size_t)s * E);
            const float4 v = *reinterpret_cast<const float4*>(Ff + (size_t)s * E + 4);
            const float a = al[s];
            acc[0] += a * u.x; acc[1] += a * u.y; acc[2] += a * u.z; acc[3] += a * u.w;
            acc[4] += a * v.x; acc[5] += a * v.y; acc[6] += a * v.z; acc[7] += a * v.w;
        }
    }
    u16x8 t;
#pragma unroll
    for (int j = 0; j < 8; ++j) t[j] = f2bf(acc[j]);
    *reinterpret_cast<u16x8*>(ctx + (size_t)b * E + e0) = t;
}

// ===========================================================================
// LSTM cell pointwise: gates fp32 -> c fp32 (in place), h bf16
// ===========================================================================
__global__ __launch_bounds__(256) void lstm_cell_bf(
    const float* __restrict__ gates, u16* __restrict__ h, float* __restrict__ c)
{
    const int idx = blockIdx.x * 256 + threadIdx.x;  // B*D
    const int b = idx >> 9;
    const int d = idx & (D - 1);
    const float* g = gates + (size_t)b * 4 * D;
    const float gi = g[d];
    const float gf = g[D + d];
    const float gg = g[2 * D + d];
    const float go = g[3 * D + d];
    const float si = 1.f / (1.f + expf(-gi));
    const float sf = 1.f / (1.f + expf(-gf));
    const float so = 1.f / (1.f + expf(-go));
    const float cn = sf * c[idx] + si * tanhf(gg);
    c[idx] = cn;
    h[idx] = f2bf(so * tanhf(cn));
}

// ===========================================================================
// ======================= OLD fp32 fallback path ============================
// (used only if ws_size is too small for the bf16 path; proven round-1 code)
// ===========================================================================
struct Pair {
    const float* Aptr; int lda; const float* Wptr; int ldw; int K;
};

template <int NP>
__global__ __launch_bounds__(256) void gemm_f32(
    int M, int N, Pair p0, Pair p1, Pair p2,
    const float* __restrict__ bias1, const float* __restrict__ bias2,
    float* __restrict__ C, long ldc)
{
    __shared__ float As[64][17];
    __shared__ float Ws[16][64];
    const int tid = threadIdx.x;
    const int row0 = blockIdx.y * 64, col0 = blockIdx.x * 64;
    const int tx = tid & 15, ty = tid >> 4;
    float acc[4][4] = {};
    Pair ps[3] = {p0, p1, p2};
#pragma unroll
    for (int p = 0; p < NP; ++p) {
        const float* Ag = ps[p].Aptr; const float* Wg = ps[p].Wptr;
        const int lda = ps[p].lda, ldw = ps[p].ldw, K = ps[p].K;
        for (int k0 = 0; k0 < K; k0 += 16) {
            {
                const int k = tid & 15, mb = tid >> 4;
#pragma unroll
                for (int i = 0; i < 4; ++i) {
                    const int m = mb + 16 * i, gr = row0 + m;
                    float v = 0.f;
                    if (gr < M) v = Ag[(size_t)gr * lda + k0 + k];
                    As[m][k] = v;
                }
            }
            {
                const int n = tid & 63, kb = tid >> 6, gc = col0 + n;
#pragma unroll
                for (int i = 0; i < 4; ++i) {
                    const int k = kb * 4 + i;
                    float v = 0.f;
                    if (gc < N) v = Wg[(size_t)(k0 + k) * ldw + gc];
                    Ws[k][n] = v;
                }
            }
            __syncthreads();
#pragma unroll
            for (int k = 0; k < 16; ++k) {
                float av[4];
#pragma unroll
                for (int i = 0; i < 4; ++i) av[i] = As[ty * 4 + i][k];
                const float4 bv = reinterpret_cast<const float4*>(&Ws[k][0])[tx];
                const float bvv[4] = {bv.x, bv.y, bv.z, bv.w};
#pragma unroll
                for (int i = 0; i < 4; ++i)
#pragma unroll
                    for (int j = 0; j < 4; ++j) acc[i][j] += av[i] * bvv[j];
            }
            __syncthreads();
        }
    }
#pragma unroll
    for (int i = 0; i < 4; ++i) {
        const int r = row0 + ty * 4 + i;
        if (r >= M) continue;
#pragma unroll
        for (int j = 0; j < 4; ++j) {
            const int cidx = col0 + tx * 4 + j;
            if (cidx >= N) continue;
            float v = acc[i][j];
            if (bias1) v += bias1[cidx];
            if (bias2) v += bias2[cidx];
            C[(size_t)r * ldc + cidx] = v;
        }
    }
}

__global__ __launch_bounds__(256) void mean_pool(const float* __restrict__ F,
                                                 float* __restrict__ mean)
{
    const int idx = blockIdx.x * 256 + threadIdx.x;
    const int b = idx >> 11, e = idx & (E - 1);
    const float* Fb = F + (size_t)b * S * E + e;
    float acc = 0.f;
    for (int s = 0; s < S; ++s) acc += Fb[(size_t)s * E];
    mean[idx] = acc * (1.f / (float)S);
}

__global__ __launch_bounds__(256) void gather_embs(const int* __restrict__ captions,
                                                   const float* __restrict__ table,
                                                   float* __restrict__ out)
{
    const int idx = blockIdx.x * 256 + threadIdx.x;
    const int per_row = EM / 4;
    const int row = idx / per_row;
    const int col = idx - row * per_row;
    const int cap = captions[row];
    reinterpret_cast<float4*>(out)[idx] =
        reinterpret_cast<const float4*>(table + (size_t)cap * EM)[col];
}

__global__ __launch_bounds__(256) void attn_softmax(
    const float* __restrict__ enc_att, const float* __restrict__ dec_att,
    const float* __restrict__ W_fa, const float* __restrict__ b_fa,
    float* __restrict__ alpha)
{
    const int b = blockIdx.x, tid = threadIdx.x;
    const int wave = tid >> 6, lane = tid & 63;
    __shared__ float dec[A], wfa[A], sc[S], redm[4], reds[4];
    dec[tid] = dec_att[b * A + tid];
    wfa[tid] = W_fa[tid];
    __syncthreads();
    for (int s = wave; s < S; s += 4) {
        const float* ea = enc_att + ((size_t)b * S + s) * A;
        float v = 0.f;
#pragma unroll
        for (int i = 0; i < 4; ++i) {
            const int a = lane + 64 * i;
            float x = ea[a] + dec[a];
            x = x > 0.f ? x : 0.f;
            v += x * wfa[a];
        }
        for (int off = 32; off; off >>= 1) v += __shfl_down(v, off);
        if (lane == 0) sc[s] = v + b_fa[0];
    }
    __syncthreads();
    float m = -1e30f;
    for (int s = tid; s < S; s += 256) m = fmaxf(m, sc[s]);
    for (int off = 32; off; off >>= 1) m = fmaxf(m, __shfl_down(m, off));
    if (lane == 0) redm[wave] = m;
    __syncthreads();
    if (tid == 0) redm[0] = fmaxf(fmaxf(redm[0], redm[1]), fmaxf(redm[2], redm[3]));
    __syncthreads();
    m = redm[0];
    float sum = 0.f;
    for (int s = tid; s < S; s += 256) {
        const float ev = expf(sc[s] - m);
        sc[s] = ev; sum += ev;
    }
    for (int off = 32; off; off >>= 1) sum += __shfl_down(sum, off);
    if (lane == 0) reds[wave] = sum;
    __syncthreads();
    if (tid == 0) reds[0] = reds[0] + reds[1] + reds[2] + reds[3];
    __syncthreads();
    const float inv = 1.f / reds[0];
    for (int s = tid; s < S; s += 256) alpha[b * S + s] = sc[s] * inv;
}

__global__ __launch_bounds__(256) void context_kernel(
    const float* __restrict__ F, const float* __restrict__ alpha,
    float* __restrict__ ctx)
{
    const int chunks = E / 256;
    const int b = blockIdx.x / chunks;
    const int ec = blockIdx.x - b * chunks;
    const int e = ec * 256 + threadIdx.x;
    __shared__ float al[S];
    for (int s = threadIdx.x; s < S; s += 256) al[s] = alpha[b * S + s];
    __syncthreads();
    const float* Fb = F + (size_t)b * S * E + e;
    float acc = 0.f;
    for (int s = 0; s < S; ++s) acc += al[s] * Fb[(size_t)s * E];
    ctx[b * E + e] = acc;
}

__global__ __launch_bounds__(256) void lstm_cell(
    const float* __restrict__ gates, float* __restrict__ h, float* __restrict__ c)
{
    const int idx = blockIdx.x * 256 + threadIdx.x;
    const int b = idx >> 9, d = idx & (D - 1);
    const float* g = gates + (size_t)b * 4 * D;
    const float gi = g[d], gf = g[D + d], gg = g[2 * D + d], go = g[3 * D + d];
    const float si = 1.f / (1.f + expf(-gi));
    const float sf = 1.f / (1.f + expf(-gf));
    const float so = 1.f / (1.f + expf(-go));
    const float cn = sf * c[idx] + si * tanhf(gg);
    c[idx] = cn;
    h[idx] = so * tanhf(cn);
}

// ===========================================================================
// launch
// ===========================================================================
extern "C" void kernel_launch(void* const* d_in, const int* in_sizes, int n_in,
                              void* d_out, int out_size, void* d_ws, size_t ws_size,
                              hipStream_t stream)
{
    const float* F        = (const float*)d_in[0];
    const int*   captions = (const int*)  d_in[1];
    const float* table    = (const float*)d_in[2];
    const float* W_ea     = (const float*)d_in[3];
    const float* b_ea     = (const float*)d_in[4];
    const float* W_da     = (const float*)d_in[5];
    const float* b_da     = (const float*)d_in[6];
    const float* W_fa     = (const float*)d_in[7];
    const float* b_fa     = (const float*)d_in[8];
    const float* W_ih     = (const float*)d_in[9];
    const float* b_ih     = (const float*)d_in[10];
    const float* W_hh     = (const float*)d_in[11];
    const float* b_hh     = (const float*)d_in[12];
    const float* W_cp     = (const float*)d_in[13];
    const float* b_cp     = (const float*)d_in[14];
    const float* W_hp     = (const float*)d_in[15];
    const float* b_hp     = (const float*)d_in[16];
    const float* W_op     = (const float*)d_in[17];
    const float* b_op     = (const float*)d_in[18];
    const float* W_inith  = (const float*)d_in[19];
    const float* b_inith  = (const float*)d_in[20];
    const float* W_initc  = (const float*)d_in[21];
    const float* b_initc  = (const float*)d_in[22];

    float* out = (float*)d_out;
    const int VP = 10048;  // V padded to 64

    // ---- workspace allocator (256 B aligned) ----
    char* base = (char*)d_ws;
    size_t off = 0;
    auto alloc = [&](size_t bytes) -> void* {
        off = (off + 255) & ~(size_t)255;
        void* p = base + off;
        off += bytes;
        return p;
    };

    u16* W_eaT    = (u16*)alloc((size_t)A * E * 2);
    u16* W_daT    = (u16*)alloc((size_t)A * D * 2);
    u16* W_ihT    = (u16*)alloc((size_t)(4 * D) * (EM + E) * 2);
    u16* W_hhT    = (u16*)alloc((size_t)(4 * D) * D * 2);
    u16* W_cpT    = (u16*)alloc((size_t)EM * E * 2);
    u16* W_hpT    = (u16*)alloc((size_t)EM * D * 2);
    u16* W_opT    = (u16*)alloc((size_t)VP * EM * 2);
    u16* W_inithT = (u16*)alloc((size_t)D * E * 2);
    u16* W_initcT = (u16*)alloc((size_t)D * E * 2);
    u16* embs     = (u16*)alloc((size_t)B * T * EM * 2);
    u16* mean_bf  = (u16*)alloc((size_t)B * E * 2);
    u16* h_bf     = (u16*)alloc((size_t)B * D * 2);
    u16* feat_bf  = (u16*)alloc((size_t)B * EM * 2);
    u16* ctx_bf   = (u16*)alloc((size_t)B * E * 2);
    u16* enc_bf   = (u16*)alloc((size_t)B * S * A * 2);
    float* c_st   = (float*)alloc((size_t)B * D * 4);
    float* dec    = (float*)alloc((size_t)B * A * 4);
    float* alpha  = (float*)alloc((size_t)B * S * 4);
    float* gates  = (float*)alloc((size_t)B * 4 * D * 4);
    const size_t need_base = off;
    u16* F_bf     = (u16*)alloc((size_t)B * S * E * 2);
    const size_t need_fbf = off;

    const bool ok_base = need_base <= ws_size;
    const bool ok_fbf  = need_fbf <= ws_size;

    if (!ok_base) {
        // ---------------- fp32 fallback (round-1 path) ----------------
        float* ws = (float*)d_ws;
        float* mean_feat = ws;  ws += B * E;
        float* h         = ws;  ws += B * D;
        float* c         = ws;  ws += B * D;
        float* enc_att   = ws;  ws += (size_t)B * S * A;
        float* fembs     = ws;  ws += (size_t)B * T * EM;
        float* fdec      = ws;  ws += B * A;
        float* falpha    = ws;  ws += B * S;
        float* fctx      = ws;  ws += B * E;
        float* fgates    = ws;  ws += B * 4 * D;
        float* ffeat     = ws;  ws += B * EM;
        const Pair ZP = {nullptr, 0, nullptr, 0, 0};
        mean_pool<<<(B * E) / 256, 256, 0, stream>>>(F, mean_feat);
        { Pair p = {mean_feat, E, W_inith, D, E};
          gemm_f32<1><<<dim3(D / 64, B / 64), 256, 0, stream>>>(B, D, p, ZP, ZP, b_inith, nullptr, h, D); }
        { Pair p = {mean_feat, E, W_initc, D, E};
          gemm_f32<1><<<dim3(D / 64, B / 64), 256, 0, stream>>>(B, D, p, ZP, ZP, b_initc, nullptr, c, D); }
        { Pair p = {F, E, W_ea, A, E};
          gemm_f32<1><<<dim3(A / 64, (B * S) / 64), 256, 0, stream>>>(B * S, A, p, ZP, ZP, b_ea, nullptr, enc_att, A); }
        gather_embs<<<(B * T * (EM / 4)) / 256, 256, 0, stream>>>(captions, table, fembs);
        for (int t = 0; t < T; ++t) {
            { Pair p = {h, D, W_da, A, D};
              gemm_f32<1><<<dim3(A / 64, B / 64), 256, 0, stream>>>(B, A, p, ZP, ZP, b_da, nullptr, fdec, A); }
            attn_softmax<<<B, 256, 0, stream>>>(enc_att, fdec, W_fa, b_fa, falpha);
            context_kernel<<<B * (E / 256), 256, 0, stream>>>(F, falpha, fctx);
            { Pair p0 = {fembs + (size_t)t * EM, T * EM, W_ih, 4 * D, EM};
              Pair p1 = {fctx, E, W_ih + (size_t)EM * 4 * D, 4 * D, E};
              Pair p2 = {h, D, W_hh, 4 * D, D};
              gemm_f32<3><<<dim3((4 * D) / 64, B / 64), 256, 0, stream>>>(B, 4 * D, p0, p1, p2, b_ih, b_hh, fgates, 4 * D); }
            lstm_cell<<<(B * D) / 256, 256, 0, stream>>>(fgates, h, c);
            { Pair p0 = {fctx, E, W_cp, EM, E};
              Pair p1 = {h, D, W_hp, EM, D};
              gemm_f32<2><<<dim3(EM / 64, B / 64), 256, 0, stream>>>(B, EM, p0, p1, ZP, b_cp, b_hp, ffeat, EM); }
            { Pair p = {ffeat, EM, W_op, V, EM};
              gemm_f32<1><<<dim3((V + 63) / 64, B / 64), 256, 0, stream>>>(B, V, p, ZP, ZP, b_op, nullptr, out + (size_t)t * V, (long)T * V); }
        }
        return;
    }

    // ---------------- bf16 MFMA path ----------------
    const PairT ZP = {nullptr, 0, nullptr, 0, 0};

    // weight transposes (fp32 [K][N] -> bf16 [Npad][K])
    transpose_bf<<<dim3(A / 32, E / 32), 256, 0, stream>>>(W_ea, E, A, W_eaT);
    transpose_bf<<<dim3(A / 32, D / 32), 256, 0, stream>>>(W_da, D, A, W_daT);
    transpose_bf<<<dim3((4 * D) / 32, (EM + E) / 32), 256, 0, stream>>>(W_ih, EM + E, 4 * D, W_ihT);
    transpose_bf<<<dim3((4 * D) / 32, D / 32), 256, 0, stream>>>(W_hh, D, 4 * D, W_hhT);
    transpose_bf<<<dim3(EM / 32, E / 32), 256, 0, stream>>>(W_cp, E, EM, W_cpT);
    transpose_bf<<<dim3(EM / 32, D / 32), 256, 0, stream>>>(W_hp, D, EM, W_hpT);
    transpose_bf<<<dim3(VP / 32, EM / 32), 256, 0, stream>>>(W_op, EM, V, W_opT);
    transpose_bf<<<dim3(D / 32, E / 32), 256, 0, stream>>>(W_inith, E, D, W_inithT);
    transpose_bf<<<dim3(D / 32, E / 32), 256, 0, stream>>>(W_initc, E, D, W_initcT);

    // mean-pool (+ optional F->bf16 convert)
    if (ok_fbf)
        conv_mean<true><<<(B * E) / 256, 256, 0, stream>>>(F, F_bf, mean_bf);
    else
        conv_mean<false><<<(B * E) / 256, 256, 0, stream>>>(F, nullptr, mean_bf);

    gather_embs_bf<<<(B * T * (EM / 8)) / 256, 256, 0, stream>>>(captions, table, embs);

    // h0 (bf16 out), c0 (fp32 out)
    { PairT p = {mean_bf, E, W_inithT, E, E};
      gemm_mfma<1, false, u16, 4, 1><<<dim3(D / 64, 1), 256, 0, stream>>>(
          D, p, ZP, ZP, b_inith, nullptr, h_bf, D); }
    { PairT p = {mean_bf, E, W_initcT, E, E};
      gemm_mfma<1, false, float, 4, 1><<<dim3(D / 64, 1), 256, 0, stream>>>(
          D, p, ZP, ZP, b_initc, nullptr, c_st, D); }

    // enc_att = F @ W_ea + b_ea -> bf16 [B*S][A]; tile 32M x 256N
    if (ok_fbf) {
        PairT p = {F_bf, E, W_eaT, E, E};
        gemm_mfma<1, false, u16, 1, 4><<<dim3(1, (B * S) / 32), 256, 0, stream>>>(
            A, p, ZP, ZP, b_ea, nullptr, enc_bf, A);
    } else {
        PairT p = {F, E, W_eaT, E, E};
        gemm_mfma<1, true, u16, 1, 4><<<dim3(1, (B * S) / 32), 256, 0, stream>>>(
            A, p, ZP, ZP, b_ea, nullptr, enc_bf, A);
    }

    // ---- per-step loop ----
    for (int t = 0; t < T; ++t) {
        { PairT p = {h_bf, D, W_daT, D, D};
          gemm_mfma<1, false, float, 4, 1><<<dim3(A / 64, 1), 256, 0, stream>>>(
              A, p, ZP, ZP, b_da, nullptr, dec, A); }

        attn_softmax_bf<<<B, 256, 0, stream>>>(enc_bf, dec, W_fa, b_fa, alpha);

        if (ok_fbf)
            context_k<true><<<B, 256, 0, stream>>>(F_bf, alpha, ctx_bf);
        else
            context_k<false><<<B, 256, 0, stream>>>(F, alpha, ctx_bf);

        { PairT p0 = {embs + (size_t)t * EM, (long)T * EM, W_ihT, EM + E, EM};
          PairT p1 = {ctx_bf, E, W_ihT + EM, EM + E, E};
          PairT p2 = {h_bf, D, W_hhT, D, D};
          gemm_mfma<3, false, float, 4, 1><<<dim3((4 * D) / 64, 1), 256, 0, stream>>>(
              4 * D, p0, p1, p2, b_ih, b_hh, gates, 4 * D); }

        lstm_cell_bf<<<(B * D) / 256, 256, 0, stream>>>(gates, h_bf, c_st);

        { PairT p0 = {ctx_bf, E, W_cpT, E, E};
          PairT p1 = {h_bf, D, W_hpT, D, D};
          gemm_mfma<2, false, u16, 4, 1><<<dim3(EM / 64, 1), 256, 0, stream>>>(
              EM, p0, p1, ZP, b_cp, b_hp, feat_bf, EM); }

        { PairT p = {feat_bf, EM, W_opT, EM, EM};
          gemm_mfma<1, false, float, 4, 1><<<dim3((V + 63) / 64, 1), 256, 0, stream>>>(
              V, p, ZP, ZP, b_op, nullptr, out + (size_t)t * V, (long)T * V); }
    }
}

// Round 3
// 4351.968 us; speedup vs baseline: 4.7243x; 1.1634x over previous
//
#include <hip/hip_runtime.h>
#include <hip/hip_bf16.h>

// Problem constants
#define B 128
#define S 196
#define E 2048
#define D 512
#define A 256
#define V 10000
#define EM 512
#define T 20

typedef unsigned short u16;
typedef __bf16 bf16x8 __attribute__((ext_vector_type(8)));
typedef float f32x4 __attribute__((ext_vector_type(4)));
typedef u16 u16x8 __attribute__((ext_vector_type(8)));
typedef u16 u16x4 __attribute__((ext_vector_type(4)));

__device__ inline u16 f2bf(float f) {
    union { float f; unsigned u; } x; x.f = f;
    return (u16)((x.u + 0x7FFFu + ((x.u >> 16) & 1u)) >> 16);
}
__device__ inline float bf2f(u16 h) {
    union { unsigned u; float f; } x; x.u = ((unsigned)h) << 16;
    return x.f;
}
__device__ inline bf16x8 ld_bf8(const u16* p) {
    return __builtin_bit_cast(bf16x8, *reinterpret_cast<const u16x8*>(p));
}
__device__ inline bf16x8 cvt_bf8(const float* p) {
    float4 u = *reinterpret_cast<const float4*>(p);
    float4 v = *reinterpret_cast<const float4*>(p + 4);
    u16x8 t;
    t[0] = f2bf(u.x); t[1] = f2bf(u.y); t[2] = f2bf(u.z); t[3] = f2bf(u.w);
    t[4] = f2bf(v.x); t[5] = f2bf(v.y); t[6] = f2bf(v.z); t[7] = f2bf(v.w);
    return __builtin_bit_cast(bf16x8, t);
}
__device__ inline float sigm(float x) { return 1.f / (1.f + expf(-x)); }

// ===========================================================================
// Generic streaming MFMA bf16 GEMM (no LDS).
// Wave tile = WTM x WTN fragments of 16x16; block = WVM x WVN waves.
// grid.x = N / (WVN*WTN*16) (B^T rows must be padded to this span)
// grid.y = M / (WVM*WTM*16)
// Fused sum of up to 3 A@B pairs + up to 2 biases.
// ===========================================================================
struct PairT {
    const void* Ap;  // bf16 (u16*) or float* when AF32
    long lda;        // elements
    const u16* Bt;   // B^T [Npad][K] bf16
    long ldb;
    int K;           // multiple of 32
};

template <int NP, bool AF32, typename OutT, int WTM, int WTN, int WVM, int WVN>
__global__ __launch_bounds__(WVM * WVN * 64) void gemm_mfma(
    int N, PairT q0, PairT q1, PairT q2,
    const float* __restrict__ bias1, const float* __restrict__ bias2,
    OutT* __restrict__ Cc, long ldc)
{
    const int tid  = threadIdx.x;
    const int w    = tid >> 6;
    const int lane = tid & 63;
    const int lr   = lane & 15;
    const int lg   = lane >> 4;
    const int mrow = blockIdx.y * (WVM * WTM * 16) + (w / WVN) * (WTM * 16);
    const int ncol = blockIdx.x * (WVN * WTN * 16) + (w % WVN) * (WTN * 16);

    f32x4 acc[WTM][WTN];
#pragma unroll
    for (int i = 0; i < WTM; ++i)
#pragma unroll
        for (int j = 0; j < WTN; ++j) acc[i][j] = (f32x4){0.f, 0.f, 0.f, 0.f};

    const PairT qs[3] = {q0, q1, q2};
#pragma unroll
    for (int p = 0; p < NP; ++p) {
        const PairT pp = qs[p];
        const int nk = pp.K >> 5;
        const u16*   Ab = (const u16*)pp.Ap;
        const float* Af = (const float*)pp.Ap;
        size_t aoff[WTM];
#pragma unroll
        for (int mi = 0; mi < WTM; ++mi)
            aoff[mi] = (size_t)(mrow + mi * 16 + lr) * pp.lda + lg * 8;
        const u16* Bp = pp.Bt + (size_t)(ncol + lr) * pp.ldb + lg * 8;

#pragma unroll 2
        for (int kk = 0; kk < nk; ++kk) {
            const int ko = kk * 32;
            bf16x8 av[WTM], bv[WTN];
#pragma unroll
            for (int mi = 0; mi < WTM; ++mi) {
                if (AF32) av[mi] = cvt_bf8(Af + aoff[mi] + ko);
                else      av[mi] = ld_bf8(Ab + aoff[mi] + ko);
            }
#pragma unroll
            for (int ni = 0; ni < WTN; ++ni)
                bv[ni] = ld_bf8(Bp + ko + (size_t)(ni * 16) * pp.ldb);
#pragma unroll
            for (int mi = 0; mi < WTM; ++mi)
#pragma unroll
                for (int ni = 0; ni < WTN; ++ni)
                    acc[mi][ni] = __builtin_amdgcn_mfma_f32_16x16x32_bf16(
                        av[mi], bv[ni], acc[mi][ni], 0, 0, 0);
        }
    }

#pragma unroll
    for (int ni = 0; ni < WTN; ++ni) {
        const int col = ncol + ni * 16 + lr;
        if (col >= N) continue;
        float bs = 0.f;
        if (bias1) bs += bias1[col];
        if (bias2) bs += bias2[col];
#pragma unroll
        for (int mi = 0; mi < WTM; ++mi) {
#pragma unroll
            for (int r = 0; r < 4; ++r) {
                const int row = mrow + mi * 16 + lg * 4 + r;
                const float v = acc[mi][ni][r] + bs;
                if constexpr (sizeof(OutT) == 2)
                    Cc[(size_t)row * ldc + col] = (OutT)f2bf(v);
                else
                    Cc[(size_t)row * ldc + col] = v;
            }
        }
    }
}

// ===========================================================================
// Gates GEMM (3 fused pairs) + LSTM cell epilogue.
// Weight cols are gate-interleaved: col' = (d>>4)*64 + g*16 + (d&15).
// Wave tile 32M x 64N (WTM=2, WTN=4: ni == gate), 4 waves all along N.
// grid = (2048/256, 128/32) = (8, 4).
// ===========================================================================
__global__ __launch_bounds__(256) void gemm_gates_lstm(
    PairT q0, PairT q1, PairT q2,
    const float* __restrict__ b_ih_, const float* __restrict__ b_hh_,
    float* __restrict__ c_io, u16* __restrict__ h_out)
{
    const int tid  = threadIdx.x;
    const int w    = tid >> 6;
    const int lane = tid & 63;
    const int lr   = lane & 15;
    const int lg   = lane >> 4;
    const int mrow = blockIdx.y * 32;
    const int ncol = blockIdx.x * 256 + w * 64;

    f32x4 acc[2][4];
#pragma unroll
    for (int i = 0; i < 2; ++i)
#pragma unroll
        for (int j = 0; j < 4; ++j) acc[i][j] = (f32x4){0.f, 0.f, 0.f, 0.f};

    const PairT qs[3] = {q0, q1, q2};
#pragma unroll
    for (int p = 0; p < 3; ++p) {
        const PairT pp = qs[p];
        const int nk = pp.K >> 5;
        const u16* Ab = (const u16*)pp.Ap;
        size_t aoff[2];
#pragma unroll
        for (int mi = 0; mi < 2; ++mi)
            aoff[mi] = (size_t)(mrow + mi * 16 + lr) * pp.lda + lg * 8;
        const u16* Bp = pp.Bt + (size_t)(ncol + lr) * pp.ldb + lg * 8;

#pragma unroll 2
        for (int kk = 0; kk < nk; ++kk) {
            const int ko = kk * 32;
            bf16x8 av[2], bv[4];
#pragma unroll
            for (int mi = 0; mi < 2; ++mi) av[mi] = ld_bf8(Ab + aoff[mi] + ko);
#pragma unroll
            for (int ni = 0; ni < 4; ++ni)
                bv[ni] = ld_bf8(Bp + ko + (size_t)(ni * 16) * pp.ldb);
#pragma unroll
            for (int mi = 0; mi < 2; ++mi)
#pragma unroll
                for (int ni = 0; ni < 4; ++ni)
                    acc[mi][ni] = __builtin_amdgcn_mfma_f32_16x16x32_bf16(
                        av[mi], bv[ni], acc[mi][ni], 0, 0, 0);
        }
    }

    // LSTM epilogue: d = nblk*16 + lr, gate g = ni.
    const int d = (blockIdx.x * 4 + w) * 16 + lr;
    float bias[4];
#pragma unroll
    for (int g = 0; g < 4; ++g) bias[g] = b_ih_[g * D + d] + b_hh_[g * D + d];

#pragma unroll
    for (int mi = 0; mi < 2; ++mi) {
#pragma unroll
        for (int r = 0; r < 4; ++r) {
            const int row = mrow + mi * 16 + lg * 4 + r;
            const float gi = acc[mi][0][r] + bias[0];
            const float gf = acc[mi][1][r] + bias[1];
            const float gg = acc[mi][2][r] + bias[2];
            const float go = acc[mi][3][r] + bias[3];
            const size_t idx = (size_t)row * D + d;
            const float cn = sigm(gf) * c_io[idx] + sigm(gi) * tanhf(gg);
            c_io[idx] = cn;
            h_out[idx] = f2bf(sigm(go) * tanhf(cn));
        }
    }
}

// ===========================================================================
// Fused per-step attention: dec_att + scores + softmax + context.
// grid = B blocks, 256 threads.
// ===========================================================================
template <bool FBF>
__global__ __launch_bounds__(256) void attn_fused(
    const void* __restrict__ Fv,       // F_bf (u16) or F (float)
    const u16*  __restrict__ enc,      // [B*S][A] bf16
    const u16*  __restrict__ h_bf,     // [B][D]
    const u16*  __restrict__ W_daT,    // [A][D] bf16
    const float* __restrict__ b_da,
    const float* __restrict__ W_fa,
    const float* __restrict__ b_fa,
    u16* __restrict__ ctx)             // [B][E] bf16
{
    const int b = blockIdx.x, tid = threadIdx.x;
    const int wave = tid >> 6, lane = tid & 63;

    __shared__ float hl[D];
    __shared__ float dec[A], wfa[A];
    __shared__ float sc[S];
    __shared__ float red[8];

    hl[tid]       = bf2f(h_bf[b * D + tid]);
    hl[tid + 256] = bf2f(h_bf[b * D + 256 + tid]);
    wfa[tid] = W_fa[tid];
    __syncthreads();

    // dec[a] = h . W_da[:,a] + b_da[a]; thread t -> a = t
    {
        float acc = 0.f;
        const u16* wr = W_daT + (size_t)tid * D;
#pragma unroll 4
        for (int i = 0; i < D / 8; ++i) {
            const u16x8 v = *reinterpret_cast<const u16x8*>(wr + i * 8);
#pragma unroll
            for (int j = 0; j < 8; ++j) acc += bf2f(v[j]) * hl[i * 8 + j];
        }
        dec[tid] = acc + b_da[tid];
    }
    __syncthreads();

    // scores: thread t handles s = t
    if (tid < S) {
        const u16* er = enc + ((size_t)b * S + tid) * A;
        float v = 0.f;
#pragma unroll 4
        for (int i = 0; i < A / 8; ++i) {
            const u16x8 e8 = *reinterpret_cast<const u16x8*>(er + i * 8);
#pragma unroll
            for (int j = 0; j < 8; ++j) {
                float x = bf2f(e8[j]) + dec[i * 8 + j];
                x = x > 0.f ? x : 0.f;
                v += x * wfa[i * 8 + j];
            }
        }
        sc[tid] = v + b_fa[0];
    }
    __syncthreads();

    // softmax (keep exp in sc, scale context by 1/sum at the end)
    float m = -1e30f;
    for (int s = tid; s < S; s += 256) m = fmaxf(m, sc[s]);
    for (int off = 32; off; off >>= 1) m = fmaxf(m, __shfl_down(m, off));
    if (lane == 0) red[wave] = m;
    __syncthreads();
    if (tid == 0) red[0] = fmaxf(fmaxf(red[0], red[1]), fmaxf(red[2], red[3]));
    __syncthreads();
    m = red[0];

    float sum = 0.f;
    for (int s = tid; s < S; s += 256) {
        const float ev = expf(sc[s] - m);
        sc[s] = ev;
        sum += ev;
    }
    for (int off = 32; off; off >>= 1) sum += __shfl_down(sum, off);
    if (lane == 0) red[4 + wave] = sum;
    __syncthreads();
    if (tid == 0) red[4] = red[4] + red[5] + red[6] + red[7];
    __syncthreads();
    const float inv = 1.f / red[4];

    // context: thread t handles e = t*8 .. t*8+7 (256*8 = 2048 = E)
    const int e0 = tid * 8;
    float acc[8] = {0.f, 0.f, 0.f, 0.f, 0.f, 0.f, 0.f, 0.f};
    if (FBF) {
        const u16* Fb = (const u16*)Fv + (size_t)b * S * E + e0;
#pragma unroll 2
        for (int s = 0; s < S; ++s) {
            const u16x8 v = *reinterpret_cast<const u16x8*>(Fb + (size_t)s * E);
            const float a = sc[s];
#pragma unroll
            for (int j = 0; j < 8; ++j) acc[j] += a * bf2f(v[j]);
        }
    } else {
        const float* Ff = (const float*)Fv + (size_t)b * S * E + e0;
#pragma unroll 2
        for (int s = 0; s < S; ++s) {
            const float4 u = *reinterpret_cast<const float4*>(Ff + (size_t)s * E);
            const float4 v = *reinterpret_cast<const float4*>(Ff + (size_t)s * E + 4);
            const float a = sc[s];
            acc[0] += a * u.x; acc[1] += a * u.y; acc[2] += a * u.z; acc[3] += a * u.w;
            acc[4] += a * v.x; acc[5] += a * v.y; acc[6] += a * v.z; acc[7] += a * v.w;
        }
    }
    u16x8 t8;
#pragma unroll
    for (int j = 0; j < 8; ++j) t8[j] = f2bf(acc[j] * inv);
    *reinterpret_cast<u16x8*>(ctx + (size_t)b * E + e0) = t8;
}

// ===========================================================================
// transpose fp32 [K][N] -> bf16 [Npad][K]; pad rows zeroed.
// grid = (Npad/32, K/32), 256 threads.
// ===========================================================================
__global__ __launch_bounds__(256) void transpose_bf(
    const float* __restrict__ in, int K, int N, u16* __restrict__ out)
{
    __shared__ float t[32][33];
    const int k0 = blockIdx.y * 32, n0 = blockIdx.x * 32;
    const int c = threadIdx.x & 31, r8 = threadIdx.x >> 5;
#pragma unroll
    for (int i = 0; i < 4; ++i) {
        const int k = r8 + i * 8;
        float v = 0.f;
        if (n0 + c < N) v = in[(size_t)(k0 + k) * N + n0 + c];
        t[k][c] = v;
    }
    __syncthreads();
#pragma unroll
    for (int i = 0; i < 4; ++i) {
        const int n = r8 + i * 8;
        out[(size_t)(n0 + n) * K + k0 + c] = f2bf(t[c][n]);
    }
}

// Same but with gate-interleave output-row permutation (N must be 2048 = 4*D):
// out row for input col n (= g*D + d): ((d>>4)<<6) + (g<<4) + (d&15)
__global__ __launch_bounds__(256) void transpose_bf_gates(
    const float* __restrict__ in, int K, u16* __restrict__ out)
{
    __shared__ float t[32][33];
    const int k0 = blockIdx.y * 32, n0 = blockIdx.x * 32;
    const int c = threadIdx.x & 31, r8 = threadIdx.x >> 5;
#pragma unroll
    for (int i = 0; i < 4; ++i) {
        const int k = r8 + i * 8;
        t[k][c] = in[(size_t)(k0 + k) * (4 * D) + n0 + c];
    }
    __syncthreads();
#pragma unroll
    for (int i = 0; i < 4; ++i) {
        const int n = n0 + r8 + i * 8;
        const int g = n >> 9, d = n & (D - 1);
        const int orow = ((d >> 4) << 6) + (g << 4) + (d & 15);
        out[(size_t)orow * K + k0 + c] = f2bf(t[c][r8 + i * 8]);
    }
}

// ===========================================================================
// fused: mean over S (fp32 acc -> bf16) and optional F -> bf16 copy
// ===========================================================================
template <bool WRITE>
__global__ __launch_bounds__(256) void conv_mean(
    const float* __restrict__ F, u16* __restrict__ Fbf, u16* __restrict__ meanbf)
{
    const int idx = blockIdx.x * 256 + threadIdx.x;  // over B*E
    const int b = idx >> 11;
    const int e = idx & (E - 1);
    const float* src = F + (size_t)b * S * E + e;
    float acc = 0.f;
#pragma unroll 2
    for (int s = 0; s < S; ++s) {
        const float v = src[(size_t)s * E];
        acc += v;
        if (WRITE) Fbf[(size_t)b * S * E + (size_t)s * E + e] = f2bf(v);
    }
    meanbf[idx] = f2bf(acc * (1.f / (float)S));
}

// ===========================================================================
// embedding gather -> bf16 embs [B][T][EM]
// ===========================================================================
__global__ __launch_bounds__(256) void gather_embs_bf(
    const int* __restrict__ captions, const float* __restrict__ table,
    u16* __restrict__ out)
{
    const int idx = blockIdx.x * 256 + threadIdx.x;  // B*T*(EM/8)
    const int row = idx >> 6;
    const int ch  = idx & 63;
    const int cap = captions[row];
    const float* src = table + (size_t)cap * EM + ch * 8;
    float4 u = *reinterpret_cast<const float4*>(src);
    float4 v = *reinterpret_cast<const float4*>(src + 4);
    u16x8 t;
    t[0] = f2bf(u.x); t[1] = f2bf(u.y); t[2] = f2bf(u.z); t[3] = f2bf(u.w);
    t[4] = f2bf(v.x); t[5] = f2bf(v.y); t[6] = f2bf(v.z); t[7] = f2bf(v.w);
    *reinterpret_cast<u16x8*>(out + (size_t)row * EM + ch * 8) = t;
}

// ===========================================================================
// ======================= fp32 fallback path ================================
// ===========================================================================
struct Pair {
    const float* Aptr; int lda; const float* Wptr; int ldw; int K;
};

template <int NP>
__global__ __launch_bounds__(256) void gemm_f32(
    int M, int N, Pair p0, Pair p1, Pair p2,
    const float* __restrict__ bias1, const float* __restrict__ bias2,
    float* __restrict__ C, long ldc)
{
    __shared__ float As[64][17];
    __shared__ float Ws[16][64];
    const int tid = threadIdx.x;
    const int row0 = blockIdx.y * 64, col0 = blockIdx.x * 64;
    const int tx = tid & 15, ty = tid >> 4;
    float acc[4][4] = {};
    Pair ps[3] = {p0, p1, p2};
#pragma unroll
    for (int p = 0; p < NP; ++p) {
        const float* Ag = ps[p].Aptr; const float* Wg = ps[p].Wptr;
        const int lda = ps[p].lda, ldw = ps[p].ldw, K = ps[p].K;
        for (int k0 = 0; k0 < K; k0 += 16) {
            {
                const int k = tid & 15, mb = tid >> 4;
#pragma unroll
                for (int i = 0; i < 4; ++i) {
                    const int m = mb + 16 * i, gr = row0 + m;
                    float v = 0.f;
                    if (gr < M) v = Ag[(size_t)gr * lda + k0 + k];
                    As[m][k] = v;
                }
            }
            {
                const int n = tid & 63, kb = tid >> 6, gc = col0 + n;
#pragma unroll
                for (int i = 0; i < 4; ++i) {
                    const int k = kb * 4 + i;
                    float v = 0.f;
                    if (gc < N) v = Wg[(size_t)(k0 + k) * ldw + gc];
                    Ws[k][n] = v;
                }
            }
            __syncthreads();
#pragma unroll
            for (int k = 0; k < 16; ++k) {
                float av[4];
#pragma unroll
                for (int i = 0; i < 4; ++i) av[i] = As[ty * 4 + i][k];
                const float4 bv = reinterpret_cast<const float4*>(&Ws[k][0])[tx];
                const float bvv[4] = {bv.x, bv.y, bv.z, bv.w};
#pragma unroll
                for (int i = 0; i < 4; ++i)
#pragma unroll
                    for (int j = 0; j < 4; ++j) acc[i][j] += av[i] * bvv[j];
            }
            __syncthreads();
        }
    }
#pragma unroll
    for (int i = 0; i < 4; ++i) {
        const int r = row0 + ty * 4 + i;
        if (r >= M) continue;
#pragma unroll
        for (int j = 0; j < 4; ++j) {
            const int cidx = col0 + tx * 4 + j;
            if (cidx >= N) continue;
            float v = acc[i][j];
            if (bias1) v += bias1[cidx];
            if (bias2) v += bias2[cidx];
            C[(size_t)r * ldc + cidx] = v;
        }
    }
}

__global__ __launch_bounds__(256) void mean_pool(const float* __restrict__ F,
                                                 float* __restrict__ mean)
{
    const int idx = blockIdx.x * 256 + threadIdx.x;
    const int b = idx >> 11, e = idx & (E - 1);
    const float* Fb = F + (size_t)b * S * E + e;
    float acc = 0.f;
    for (int s = 0; s < S; ++s) acc += Fb[(size_t)s * E];
    mean[idx] = acc * (1.f / (float)S);
}

__global__ __launch_bounds__(256) void gather_embs(const int* __restrict__ captions,
                                                   const float* __restrict__ table,
                                                   float* __restrict__ out)
{
    const int idx = blockIdx.x * 256 + threadIdx.x;
    const int per_row = EM / 4;
    const int row = idx / per_row;
    const int col = idx - row * per_row;
    const int cap = captions[row];
    reinterpret_cast<float4*>(out)[idx] =
        reinterpret_cast<const float4*>(table + (size_t)cap * EM)[col];
}

__global__ __launch_bounds__(256) void attn_softmax(
    const float* __restrict__ enc_att, const float* __restrict__ dec_att,
    const float* __restrict__ W_fa, const float* __restrict__ b_fa,
    float* __restrict__ alpha)
{
    const int b = blockIdx.x, tid = threadIdx.x;
    const int wave = tid >> 6, lane = tid & 63;
    __shared__ float dec[A], wfa[A], sc[S], redm[4], reds[4];
    dec[tid] = dec_att[b * A + tid];
    wfa[tid] = W_fa[tid];
    __syncthreads();
    for (int s = wave; s < S; s += 4) {
        const float* ea = enc_att + ((size_t)b * S + s) * A;
        float v = 0.f;
#pragma unroll
        for (int i = 0; i < 4; ++i) {
            const int a = lane + 64 * i;
            float x = ea[a] + dec[a];
            x = x > 0.f ? x : 0.f;
            v += x * wfa[a];
        }
        for (int off = 32; off; off >>= 1) v += __shfl_down(v, off);
        if (lane == 0) sc[s] = v + b_fa[0];
    }
    __syncthreads();
    float m = -1e30f;
    for (int s = tid; s < S; s += 256) m = fmaxf(m, sc[s]);
    for (int off = 32; off; off >>= 1) m = fmaxf(m, __shfl_down(m, off));
    if (lane == 0) redm[wave] = m;
    __syncthreads();
    if (tid == 0) redm[0] = fmaxf(fmaxf(redm[0], redm[1]), fmaxf(redm[2], redm[3]));
    __syncthreads();
    m = redm[0];
    float sum = 0.f;
    for (int s = tid; s < S; s += 256) {
        const float ev = expf(sc[s] - m);
        sc[s] = ev; sum += ev;
    }
    for (int off = 32; off; off >>= 1) sum += __shfl_down(sum, off);
    if (lane == 0) reds[wave] = sum;
    __syncthreads();
    if (tid == 0) reds[0] = reds[0] + reds[1] + reds[2] + reds[3];
    __syncthreads();
    const float inv = 1.f / reds[0];
    for (int s = tid; s < S; s += 256) alpha[b * S + s] = sc[s] * inv;
}

__global__ __launch_bounds__(256) void context_kernel(
    const float* __restrict__ F, const float* __restrict__ alpha,
    float* __restrict__ ctx)
{
    const int chunks = E / 256;
    const int b = blockIdx.x / chunks;
    const int ec = blockIdx.x - b * chunks;
    const int e = ec * 256 + threadIdx.x;
    __shared__ float al[S];
    for (int s = threadIdx.x; s < S; s += 256) al[s] = alpha[b * S + s];
    __syncthreads();
    const float* Fb = F + (size_t)b * S * E + e;
    float acc = 0.f;
    for (int s = 0; s < S; ++s) acc += al[s] * Fb[(size_t)s * E];
    ctx[b * E + e] = acc;
}

__global__ __launch_bounds__(256) void lstm_cell(
    const float* __restrict__ gates, float* __restrict__ h, float* __restrict__ c)
{
    const int idx = blockIdx.x * 256 + threadIdx.x;
    const int b = idx >> 9, d = idx & (D - 1);
    const float* g = gates + (size_t)b * 4 * D;
    const float gi = g[d], gf = g[D + d], gg = g[2 * D + d], go = g[3 * D + d];
    const float cn = sigm(gf) * c[idx] + sigm(gi) * tanhf(gg);
    c[idx] = cn;
    h[idx] = sigm(go) * tanhf(cn);
}

// ===========================================================================
// launch
// ===========================================================================
extern "C" void kernel_launch(void* const* d_in, const int* in_sizes, int n_in,
                              void* d_out, int out_size, void* d_ws, size_t ws_size,
                              hipStream_t stream)
{
    const float* F        = (const float*)d_in[0];
    const int*   captions = (const int*)  d_in[1];
    const float* table    = (const float*)d_in[2];
    const float* W_ea     = (const float*)d_in[3];
    const float* b_ea     = (const float*)d_in[4];
    const float* W_da     = (const float*)d_in[5];
    const float* b_da     = (const float*)d_in[6];
    const float* W_fa     = (const float*)d_in[7];
    const float* b_fa     = (const float*)d_in[8];
    const float* W_ih     = (const float*)d_in[9];
    const float* b_ih     = (const float*)d_in[10];
    const float* W_hh     = (const float*)d_in[11];
    const float* b_hh     = (const float*)d_in[12];
    const float* W_cp     = (const float*)d_in[13];
    const float* b_cp     = (const float*)d_in[14];
    const float* W_hp     = (const float*)d_in[15];
    const float* b_hp     = (const float*)d_in[16];
    const float* W_op     = (const float*)d_in[17];
    const float* b_op     = (const float*)d_in[18];
    const float* W_inith  = (const float*)d_in[19];
    const float* b_inith  = (const float*)d_in[20];
    const float* W_initc  = (const float*)d_in[21];
    const float* b_initc  = (const float*)d_in[22];

    float* out = (float*)d_out;
    const int VP2 = 10240;  // V padded to 256-span

    // ---- workspace allocator (256 B aligned) ----
    char* base = (char*)d_ws;
    size_t off = 0;
    auto alloc = [&](size_t bytes) -> void* {
        off = (off + 255) & ~(size_t)255;
        void* p = base + off;
        off += bytes;
        return p;
    };

    u16* W_eaT    = (u16*)alloc((size_t)A * E * 2);
    u16* W_daT    = (u16*)alloc((size_t)A * D * 2);
    u16* W_ihT    = (u16*)alloc((size_t)(4 * D) * (EM + E) * 2);  // gate-interleaved
    u16* W_hhT    = (u16*)alloc((size_t)(4 * D) * D * 2);         // gate-interleaved
    u16* W_cpT    = (u16*)alloc((size_t)EM * E * 2);
    u16* W_hpT    = (u16*)alloc((size_t)EM * D * 2);
    u16* W_opT    = (u16*)alloc((size_t)VP2 * EM * 2);
    u16* W_inithT = (u16*)alloc((size_t)D * E * 2);
    u16* W_initcT = (u16*)alloc((size_t)D * E * 2);
    u16* embs     = (u16*)alloc((size_t)B * T * EM * 2);
    u16* mean_bf  = (u16*)alloc((size_t)B * E * 2);
    u16* h_bf     = (u16*)alloc((size_t)B * D * 2);
    u16* feat_bf  = (u16*)alloc((size_t)B * EM * 2);
    u16* ctx_bf   = (u16*)alloc((size_t)B * E * 2);
    u16* enc_bf   = (u16*)alloc((size_t)B * S * A * 2);
    float* c_st   = (float*)alloc((size_t)B * D * 4);
    const size_t need_base = off;
    u16* F_bf     = (u16*)alloc((size_t)B * S * E * 2);
    const size_t need_fbf = off;

    const bool ok_base = need_base <= ws_size;
    const bool ok_fbf  = need_fbf <= ws_size;

    if (!ok_base) {
        // ---------------- fp32 fallback ----------------
        float* ws = (float*)d_ws;
        float* mean_feat = ws;  ws += B * E;
        float* h         = ws;  ws += B * D;
        float* c         = ws;  ws += B * D;
        float* enc_att   = ws;  ws += (size_t)B * S * A;
        float* fembs     = ws;  ws += (size_t)B * T * EM;
        float* fdec      = ws;  ws += B * A;
        float* falpha    = ws;  ws += B * S;
        float* fctx      = ws;  ws += B * E;
        float* fgates    = ws;  ws += B * 4 * D;
        float* ffeat     = ws;  ws += B * EM;
        const Pair ZP = {nullptr, 0, nullptr, 0, 0};
        mean_pool<<<(B * E) / 256, 256, 0, stream>>>(F, mean_feat);
        { Pair p = {mean_feat, E, W_inith, D, E};
          gemm_f32<1><<<dim3(D / 64, B / 64), 256, 0, stream>>>(B, D, p, ZP, ZP, b_inith, nullptr, h, D); }
        { Pair p = {mean_feat, E, W_initc, D, E};
          gemm_f32<1><<<dim3(D / 64, B / 64), 256, 0, stream>>>(B, D, p, ZP, ZP, b_initc, nullptr, c, D); }
        { Pair p = {F, E, W_ea, A, E};
          gemm_f32<1><<<dim3(A / 64, (B * S) / 64), 256, 0, stream>>>(B * S, A, p, ZP, ZP, b_ea, nullptr, enc_att, A); }
        gather_embs<<<(B * T * (EM / 4)) / 256, 256, 0, stream>>>(captions, table, fembs);
        for (int t = 0; t < T; ++t) {
            { Pair p = {h, D, W_da, A, D};
              gemm_f32<1><<<dim3(A / 64, B / 64), 256, 0, stream>>>(B, A, p, ZP, ZP, b_da, nullptr, fdec, A); }
            attn_softmax<<<B, 256, 0, stream>>>(enc_att, fdec, W_fa, b_fa, falpha);
            context_kernel<<<B * (E / 256), 256, 0, stream>>>(F, falpha, fctx);
            { Pair p0 = {fembs + (size_t)t * EM, T * EM, W_ih, 4 * D, EM};
              Pair p1 = {fctx, E, W_ih + (size_t)EM * 4 * D, 4 * D, E};
              Pair p2 = {h, D, W_hh, 4 * D, D};
              gemm_f32<3><<<dim3((4 * D) / 64, B / 64), 256, 0, stream>>>(B, 4 * D, p0, p1, p2, b_ih, b_hh, fgates, 4 * D); }
            lstm_cell<<<(B * D) / 256, 256, 0, stream>>>(fgates, h, c);
            { Pair p0 = {fctx, E, W_cp, EM, E};
              Pair p1 = {h, D, W_hp, EM, D};
              gemm_f32<2><<<dim3(EM / 64, B / 64), 256, 0, stream>>>(B, EM, p0, p1, ZP, b_cp, b_hp, ffeat, EM); }
            { Pair p = {ffeat, EM, W_op, V, EM};
              gemm_f32<1><<<dim3((V + 63) / 64, B / 64), 256, 0, stream>>>(B, V, p, ZP, ZP, b_op, nullptr, out + (size_t)t * V, (long)T * V); }
        }
        return;
    }

    // ---------------- bf16 MFMA path ----------------
    const PairT ZP = {nullptr, 0, nullptr, 0, 0};

    // weight transposes
    transpose_bf<<<dim3(A / 32, E / 32), 256, 0, stream>>>(W_ea, E, A, W_eaT);
    transpose_bf<<<dim3(A / 32, D / 32), 256, 0, stream>>>(W_da, D, A, W_daT);
    transpose_bf_gates<<<dim3((4 * D) / 32, (EM + E) / 32), 256, 0, stream>>>(W_ih, EM + E, W_ihT);
    transpose_bf_gates<<<dim3((4 * D) / 32, D / 32), 256, 0, stream>>>(W_hh, D, W_hhT);
    transpose_bf<<<dim3(EM / 32, E / 32), 256, 0, stream>>>(W_cp, E, EM, W_cpT);
    transpose_bf<<<dim3(EM / 32, D / 32), 256, 0, stream>>>(W_hp, D, EM, W_hpT);
    transpose_bf<<<dim3(VP2 / 32, EM / 32), 256, 0, stream>>>(W_op, EM, V, W_opT);
    transpose_bf<<<dim3(D / 32, E / 32), 256, 0, stream>>>(W_inith, E, D, W_inithT);
    transpose_bf<<<dim3(D / 32, E / 32), 256, 0, stream>>>(W_initc, E, D, W_initcT);

    if (ok_fbf)
        conv_mean<true><<<(B * E) / 256, 256, 0, stream>>>(F, F_bf, mean_bf);
    else
        conv_mean<false><<<(B * E) / 256, 256, 0, stream>>>(F, nullptr, mean_bf);

    gather_embs_bf<<<(B * T * (EM / 8)) / 256, 256, 0, stream>>>(captions, table, embs);

    // h0 (bf16), c0 (fp32). wave tile 32x64, 4 waves along N: grid (2, 4)
    { PairT p = {mean_bf, E, W_inithT, E, E};
      gemm_mfma<1, false, u16, 2, 4, 1, 4><<<dim3(2, 4), 256, 0, stream>>>(
          D, p, ZP, ZP, b_inith, nullptr, h_bf, D); }
    { PairT p = {mean_bf, E, W_initcT, E, E};
      gemm_mfma<1, false, float, 2, 4, 1, 4><<<dim3(2, 4), 256, 0, stream>>>(
          D, p, ZP, ZP, b_initc, nullptr, c_st, D); }

    // enc_att: 64x64 wave tiles, 2x2 waves -> block 128M x 128N, grid (2, 196)
    if (ok_fbf) {
        PairT p = {F_bf, E, W_eaT, E, E};
        gemm_mfma<1, false, u16, 4, 4, 2, 2><<<dim3(2, (B * S) / 128), 256, 0, stream>>>(
            A, p, ZP, ZP, b_ea, nullptr, enc_bf, A);
    } else {
        PairT p = {F, E, W_eaT, E, E};
        gemm_mfma<1, true, u16, 4, 4, 2, 2><<<dim3(2, (B * S) / 128), 256, 0, stream>>>(
            A, p, ZP, ZP, b_ea, nullptr, enc_bf, A);
    }

    // ---- per-step loop: 4 kernels/step ----
    for (int t = 0; t < T; ++t) {
        if (ok_fbf)
            attn_fused<true><<<B, 256, 0, stream>>>(
                F_bf, enc_bf, h_bf, W_daT, b_da, W_fa, b_fa, ctx_bf);
        else
            attn_fused<false><<<B, 256, 0, stream>>>(
                F, enc_bf, h_bf, W_daT, b_da, W_fa, b_fa, ctx_bf);

        { PairT p0 = {embs + (size_t)t * EM, (long)T * EM, W_ihT, EM + E, EM};
          PairT p1 = {ctx_bf, E, W_ihT + EM, EM + E, E};
          PairT p2 = {h_bf, D, W_hhT, D, D};
          gemm_gates_lstm<<<dim3(8, 4), 256, 0, stream>>>(
              p0, p1, p2, b_ih, b_hh, c_st, h_bf); }

        { PairT p0 = {ctx_bf, E, W_cpT, E, E};
          PairT p1 = {h_bf, D, W_hpT, D, D};
          gemm_mfma<2, false, u16, 2, 4, 1, 4><<<dim3(2, 4), 256, 0, stream>>>(
              EM, p0, p1, ZP, b_cp, b_hp, feat_bf, EM); }

        { PairT p = {feat_bf, EM, W_opT, EM, EM};
          gemm_mfma<1, false, float, 2, 4, 1, 4><<<dim3(VP2 / 256, 4), 256, 0, stream>>>(
              V, p, ZP, ZP, b_op, nullptr, out + (size_t)t * V, (long)T * V); }
    }
}

// Round 4
// 2115.763 us; speedup vs baseline: 9.7175x; 2.0569x over previous
//
#include <hip/hip_runtime.h>
#include <hip/hip_bf16.h>

// Problem constants
#define B 128
#define S 196
#define E 2048
#define D 512
#define A 256
#define V 10000
#define EM 512
#define T 20

typedef unsigned short u16;
typedef __bf16 bf16x8 __attribute__((ext_vector_type(8)));
typedef float f32x4 __attribute__((ext_vector_type(4)));
typedef u16 u16x8 __attribute__((ext_vector_type(8)));
typedef u16 u16x4 __attribute__((ext_vector_type(4)));

__device__ inline u16 f2bf(float f) {
    union { float f; unsigned u; } x; x.f = f;
    return (u16)((x.u + 0x7FFFu + ((x.u >> 16) & 1u)) >> 16);
}
__device__ inline float bf2f(u16 h) {
    union { unsigned u; float f; } x; x.u = ((unsigned)h) << 16;
    return x.f;
}
__device__ inline bf16x8 ld_bf8(const u16* p) {
    return __builtin_bit_cast(bf16x8, *reinterpret_cast<const u16x8*>(p));
}
__device__ inline bf16x8 cvt_bf8(const float* p) {
    float4 u = *reinterpret_cast<const float4*>(p);
    float4 v = *reinterpret_cast<const float4*>(p + 4);
    u16x8 t;
    t[0] = f2bf(u.x); t[1] = f2bf(u.y); t[2] = f2bf(u.z); t[3] = f2bf(u.w);
    t[4] = f2bf(v.x); t[5] = f2bf(v.y); t[6] = f2bf(v.z); t[7] = f2bf(v.w);
    return __builtin_bit_cast(bf16x8, t);
}
__device__ inline float sigm(float x) { return 1.f / (1.f + expf(-x)); }

// ===========================================================================
// Generic streaming MFMA bf16 GEMM (no LDS).
// Wave tile = WTM x WTN fragments of 16x16; block = WVM x WVN waves.
// grid.x = N / (WVN*WTN*16) (B^T rows must be padded to this span)
// grid.y = M / (WVM*WTM*16)
// ===========================================================================
struct PairT {
    const void* Ap;  // bf16 (u16*) or float* when AF32
    long lda;        // elements
    const u16* Bt;   // B^T [Npad][K] bf16
    long ldb;
    int K;           // multiple of 32
};

template <int NP, bool AF32, typename OutT, int WTM, int WTN, int WVM, int WVN>
__global__ __launch_bounds__(WVM * WVN * 64) void gemm_mfma(
    int N, PairT q0, PairT q1, PairT q2,
    const float* __restrict__ bias1, const float* __restrict__ bias2,
    OutT* __restrict__ Cc, long ldc)
{
    const int tid  = threadIdx.x;
    const int w    = tid >> 6;
    const int lane = tid & 63;
    const int lr   = lane & 15;
    const int lg   = lane >> 4;
    const int mrow = blockIdx.y * (WVM * WTM * 16) + (w / WVN) * (WTM * 16);
    const int ncol = blockIdx.x * (WVN * WTN * 16) + (w % WVN) * (WTN * 16);

    f32x4 acc[WTM][WTN];
#pragma unroll
    for (int i = 0; i < WTM; ++i)
#pragma unroll
        for (int j = 0; j < WTN; ++j) acc[i][j] = (f32x4){0.f, 0.f, 0.f, 0.f};

    const PairT qs[3] = {q0, q1, q2};
#pragma unroll
    for (int p = 0; p < NP; ++p) {
        const PairT pp = qs[p];
        const int nk = pp.K >> 5;
        const u16*   Ab = (const u16*)pp.Ap;
        const float* Af = (const float*)pp.Ap;
        size_t aoff[WTM];
#pragma unroll
        for (int mi = 0; mi < WTM; ++mi)
            aoff[mi] = (size_t)(mrow + mi * 16 + lr) * pp.lda + lg * 8;
        const u16* Bp = pp.Bt + (size_t)(ncol + lr) * pp.ldb + lg * 8;

#pragma unroll 2
        for (int kk = 0; kk < nk; ++kk) {
            const int ko = kk * 32;
            bf16x8 av[WTM], bv[WTN];
#pragma unroll
            for (int mi = 0; mi < WTM; ++mi) {
                if (AF32) av[mi] = cvt_bf8(Af + aoff[mi] + ko);
                else      av[mi] = ld_bf8(Ab + aoff[mi] + ko);
            }
#pragma unroll
            for (int ni = 0; ni < WTN; ++ni)
                bv[ni] = ld_bf8(Bp + ko + (size_t)(ni * 16) * pp.ldb);
#pragma unroll
            for (int mi = 0; mi < WTM; ++mi)
#pragma unroll
                for (int ni = 0; ni < WTN; ++ni)
                    acc[mi][ni] = __builtin_amdgcn_mfma_f32_16x16x32_bf16(
                        av[mi], bv[ni], acc[mi][ni], 0, 0, 0);
        }
    }

#pragma unroll
    for (int ni = 0; ni < WTN; ++ni) {
        const int col = ncol + ni * 16 + lr;
        if (col >= N) continue;
        float bs = 0.f;
        if (bias1) bs += bias1[col];
        if (bias2) bs += bias2[col];
#pragma unroll
        for (int mi = 0; mi < WTM; ++mi) {
#pragma unroll
            for (int r = 0; r < 4; ++r) {
                const int row = mrow + mi * 16 + lg * 4 + r;
                const float v = acc[mi][ni][r] + bs;
                if constexpr (sizeof(OutT) == 2)
                    Cc[(size_t)row * ldc + col] = (OutT)f2bf(v);
                else
                    Cc[(size_t)row * ldc + col] = v;
            }
        }
    }
}

// ===========================================================================
// Gates GEMM with split-K over grid.z (4 chunks = 4 operand pairs).
// Wave tile 16M x 64N, 2 waves/block (128N). grid = (16, 8, 4), 128 threads.
// Writes fp32 partials part[z][B][2048] (gate-interleaved cols).
// ===========================================================================
__global__ __launch_bounds__(128) void gates_split(
    PairT q0, PairT q1, PairT q2, PairT q3,
    float* __restrict__ part)
{
    const int tid  = threadIdx.x;
    const int w    = tid >> 6;
    const int lane = tid & 63;
    const int lr   = lane & 15;
    const int lg   = lane >> 4;
    const int z    = blockIdx.z;
    const int mrow = blockIdx.y * 16;
    const int ncol = blockIdx.x * 128 + w * 64;

    const PairT pp = (z == 0) ? q0 : (z == 1) ? q1 : (z == 2) ? q2 : q3;

    f32x4 acc[4];
#pragma unroll
    for (int j = 0; j < 4; ++j) acc[j] = (f32x4){0.f, 0.f, 0.f, 0.f};

    const int nk = pp.K >> 5;
    const u16* Ab = (const u16*)pp.Ap;
    const size_t aoff = (size_t)(mrow + lr) * pp.lda + lg * 8;
    const u16* Bp = pp.Bt + (size_t)(ncol + lr) * pp.ldb + lg * 8;

#pragma unroll 2
    for (int kk = 0; kk < nk; ++kk) {
        const int ko = kk * 32;
        const bf16x8 av = ld_bf8(Ab + aoff + ko);
        bf16x8 bv[4];
#pragma unroll
        for (int ni = 0; ni < 4; ++ni)
            bv[ni] = ld_bf8(Bp + ko + (size_t)(ni * 16) * pp.ldb);
#pragma unroll
        for (int ni = 0; ni < 4; ++ni)
            acc[ni] = __builtin_amdgcn_mfma_f32_16x16x32_bf16(av, bv[ni], acc[ni], 0, 0, 0);
    }

#pragma unroll
    for (int ni = 0; ni < 4; ++ni) {
        const int col = ncol + ni * 16 + lr;
#pragma unroll
        for (int r = 0; r < 4; ++r) {
            const int row = mrow + lg * 4 + r;
            part[((size_t)(z * B + row)) * 2048 + col] = acc[ni][r];
        }
    }
}

// ===========================================================================
// LSTM finish: sum 4 split-K partials + biases -> gates -> c, h_cur, h_all[t]
// grid = B*D/256 = 256 blocks.
// ===========================================================================
__global__ __launch_bounds__(256) void lstm_finish(
    const float* __restrict__ part,
    const float* __restrict__ b_ih_, const float* __restrict__ b_hh_,
    float* __restrict__ c_io, u16* __restrict__ h_cur,
    u16* __restrict__ h_all, int t)
{
    const int idx = blockIdx.x * 256 + threadIdx.x;  // B*D
    const int b = idx >> 9;
    const int d = idx & (D - 1);
    float g4[4];
#pragma unroll
    for (int g = 0; g < 4; ++g) {
        const int col = ((d >> 4) << 6) + (g << 4) + (d & 15);
        float s = b_ih_[g * D + d] + b_hh_[g * D + d];
#pragma unroll
        for (int z = 0; z < 4; ++z)
            s += part[((size_t)(z * B + b)) * 2048 + col];
        g4[g] = s;
    }
    const float cn = sigm(g4[1]) * c_io[idx] + sigm(g4[0]) * tanhf(g4[2]);
    c_io[idx] = cn;
    const u16 hv = f2bf(sigm(g4[3]) * tanhf(cn));
    h_cur[idx] = hv;
    h_all[((size_t)(b * T + t)) * D + d] = hv;
}

// ===========================================================================
// attn_alpha: dec_att GEMV + scores + softmax -> alpha[B][S] fp32.
// grid = B, 256 threads.
// ===========================================================================
__global__ __launch_bounds__(256) void attn_alpha(
    const u16*  __restrict__ enc,      // [B*S][A] bf16
    const u16*  __restrict__ h_cur,    // [B][D]
    const u16*  __restrict__ W_daT,    // [A][D] bf16
    const float* __restrict__ b_da,
    const float* __restrict__ W_fa,
    const float* __restrict__ b_fa,
    float* __restrict__ alpha)
{
    const int b = blockIdx.x, tid = threadIdx.x;
    const int wave = tid >> 6, lane = tid & 63;

    __shared__ float hl[D];
    __shared__ float dec[A], wfa[A];
    __shared__ float sc[S];
    __shared__ float red[8];

    hl[tid]       = bf2f(h_cur[b * D + tid]);
    hl[tid + 256] = bf2f(h_cur[b * D + 256 + tid]);
    wfa[tid] = W_fa[tid];
    __syncthreads();

    // dec[a] = h . W_da[:,a] + b_da[a]
    {
        float acc = 0.f;
        const u16* wr = W_daT + (size_t)tid * D;
#pragma unroll 4
        for (int i = 0; i < D / 8; ++i) {
            const u16x8 v = *reinterpret_cast<const u16x8*>(wr + i * 8);
#pragma unroll
            for (int j = 0; j < 8; ++j) acc += bf2f(v[j]) * hl[i * 8 + j];
        }
        dec[tid] = acc + b_da[tid];
    }
    __syncthreads();

    if (tid < S) {
        const u16* er = enc + ((size_t)b * S + tid) * A;
        float v = 0.f;
#pragma unroll 4
        for (int i = 0; i < A / 8; ++i) {
            const u16x8 e8 = *reinterpret_cast<const u16x8*>(er + i * 8);
#pragma unroll
            for (int j = 0; j < 8; ++j) {
                float x = bf2f(e8[j]) + dec[i * 8 + j];
                x = x > 0.f ? x : 0.f;
                v += x * wfa[i * 8 + j];
            }
        }
        sc[tid] = v + b_fa[0];
    }
    __syncthreads();

    float m = -1e30f;
    for (int s = tid; s < S; s += 256) m = fmaxf(m, sc[s]);
    for (int off = 32; off; off >>= 1) m = fmaxf(m, __shfl_down(m, off));
    if (lane == 0) red[wave] = m;
    __syncthreads();
    if (tid == 0) red[0] = fmaxf(fmaxf(red[0], red[1]), fmaxf(red[2], red[3]));
    __syncthreads();
    m = red[0];

    float sum = 0.f;
    for (int s = tid; s < S; s += 256) {
        const float ev = expf(sc[s] - m);
        sc[s] = ev;
        sum += ev;
    }
    for (int off = 32; off; off >>= 1) sum += __shfl_down(sum, off);
    if (lane == 0) red[4 + wave] = sum;
    __syncthreads();
    if (tid == 0) red[4] = red[4] + red[5] + red[6] + red[7];
    __syncthreads();
    const float inv = 1.f / red[4];
    for (int s = tid; s < S; s += 256) alpha[b * S + s] = sc[s] * inv;
}

// ===========================================================================
// context_wide: ctx_all[b*T+t][e] = sum_s alpha[b,s] * F[b,s,e]
// grid = B*2 blocks (b, half of E), 256 threads, 4 e's per thread.
// ===========================================================================
template <bool FBF>
__global__ __launch_bounds__(256) void context_wide(
    const void* __restrict__ Fv, const float* __restrict__ alpha,
    u16* __restrict__ ctx_all, int t)
{
    const int b    = blockIdx.x >> 1;
    const int half = blockIdx.x & 1;
    const int tid  = threadIdx.x;
    const int e0   = half * 1024 + tid * 4;

    __shared__ float al[S];
    for (int s = tid; s < S; s += 256) al[s] = alpha[b * S + s];
    __syncthreads();

    float a0 = 0.f, a1 = 0.f, a2 = 0.f, a3 = 0.f;
    if (FBF) {
        const u16* Fb = (const u16*)Fv + (size_t)b * S * E + e0;
#pragma unroll 2
        for (int s = 0; s < S; ++s) {
            const u16x4 v = *reinterpret_cast<const u16x4*>(Fb + (size_t)s * E);
            const float a = al[s];
            a0 += a * bf2f(v[0]); a1 += a * bf2f(v[1]);
            a2 += a * bf2f(v[2]); a3 += a * bf2f(v[3]);
        }
    } else {
        const float* Ff = (const float*)Fv + (size_t)b * S * E + e0;
#pragma unroll 2
        for (int s = 0; s < S; ++s) {
            const float4 u = *reinterpret_cast<const float4*>(Ff + (size_t)s * E);
            const float a = al[s];
            a0 += a * u.x; a1 += a * u.y; a2 += a * u.z; a3 += a * u.w;
        }
    }
    u16x4 o;
    o[0] = f2bf(a0); o[1] = f2bf(a1); o[2] = f2bf(a2); o[3] = f2bf(a3);
    *reinterpret_cast<u16x4*>(ctx_all + ((size_t)(b * T + t)) * E + e0) = o;
}

// ===========================================================================
// transpose fp32 [K][N] -> bf16 [Npad][K]; pad rows zeroed.
// ===========================================================================
__global__ __launch_bounds__(256) void transpose_bf(
    const float* __restrict__ in, int K, int N, u16* __restrict__ out)
{
    __shared__ float t[32][33];
    const int k0 = blockIdx.y * 32, n0 = blockIdx.x * 32;
    const int c = threadIdx.x & 31, r8 = threadIdx.x >> 5;
#pragma unroll
    for (int i = 0; i < 4; ++i) {
        const int k = r8 + i * 8;
        float v = 0.f;
        if (n0 + c < N) v = in[(size_t)(k0 + k) * N + n0 + c];
        t[k][c] = v;
    }
    __syncthreads();
#pragma unroll
    for (int i = 0; i < 4; ++i) {
        const int n = r8 + i * 8;
        out[(size_t)(n0 + n) * K + k0 + c] = f2bf(t[c][n]);
    }
}

// Gate-interleaved variant (N = 2048 = 4*D): out row for col n (= g*D+d):
// ((d>>4)<<6) + (g<<4) + (d&15)
__global__ __launch_bounds__(256) void transpose_bf_gates(
    const float* __restrict__ in, int K, u16* __restrict__ out)
{
    __shared__ float t[32][33];
    const int k0 = blockIdx.y * 32, n0 = blockIdx.x * 32;
    const int c = threadIdx.x & 31, r8 = threadIdx.x >> 5;
#pragma unroll
    for (int i = 0; i < 4; ++i) {
        const int k = r8 + i * 8;
        t[k][c] = in[(size_t)(k0 + k) * (4 * D) + n0 + c];
    }
    __syncthreads();
#pragma unroll
    for (int i = 0; i < 4; ++i) {
        const int n = n0 + r8 + i * 8;
        const int g = n >> 9, d = n & (D - 1);
        const int orow = ((d >> 4) << 6) + (g << 4) + (d & 15);
        out[(size_t)orow * K + k0 + c] = f2bf(t[c][r8 + i * 8]);
    }
}

// ===========================================================================
// fused: mean over S (fp32 acc -> bf16) and optional F -> bf16 copy
// ===========================================================================
template <bool WRITE>
__global__ __launch_bounds__(256) void conv_mean(
    const float* __restrict__ F, u16* __restrict__ Fbf, u16* __restrict__ meanbf)
{
    const int idx = blockIdx.x * 256 + threadIdx.x;  // over B*E
    const int b = idx >> 11;
    const int e = idx & (E - 1);
    const float* src = F + (size_t)b * S * E + e;
    float acc = 0.f;
#pragma unroll 2
    for (int s = 0; s < S; ++s) {
        const float v = src[(size_t)s * E];
        acc += v;
        if (WRITE) Fbf[(size_t)b * S * E + (size_t)s * E + e] = f2bf(v);
    }
    meanbf[idx] = f2bf(acc * (1.f / (float)S));
}

// ===========================================================================
// embedding gather -> bf16 embs [B][T][EM]
// ===========================================================================
__global__ __launch_bounds__(256) void gather_embs_bf(
    const int* __restrict__ captions, const float* __restrict__ table,
    u16* __restrict__ out)
{
    const int idx = blockIdx.x * 256 + threadIdx.x;  // B*T*(EM/8)
    const int row = idx >> 6;
    const int ch  = idx & 63;
    const int cap = captions[row];
    const float* src = table + (size_t)cap * EM + ch * 8;
    float4 u = *reinterpret_cast<const float4*>(src);
    float4 v = *reinterpret_cast<const float4*>(src + 4);
    u16x8 t;
    t[0] = f2bf(u.x); t[1] = f2bf(u.y); t[2] = f2bf(u.z); t[3] = f2bf(u.w);
    t[4] = f2bf(v.x); t[5] = f2bf(v.y); t[6] = f2bf(v.z); t[7] = f2bf(v.w);
    *reinterpret_cast<u16x8*>(out + (size_t)row * EM + ch * 8) = t;
}

// ===========================================================================
// ======================= fp32 fallback path ================================
// ===========================================================================
struct Pair {
    const float* Aptr; int lda; const float* Wptr; int ldw; int K;
};

template <int NP>
__global__ __launch_bounds__(256) void gemm_f32(
    int M, int N, Pair p0, Pair p1, Pair p2,
    const float* __restrict__ bias1, const float* __restrict__ bias2,
    float* __restrict__ C, long ldc)
{
    __shared__ float As[64][17];
    __shared__ float Ws[16][64];
    const int tid = threadIdx.x;
    const int row0 = blockIdx.y * 64, col0 = blockIdx.x * 64;
    const int tx = tid & 15, ty = tid >> 4;
    float acc[4][4] = {};
    Pair ps[3] = {p0, p1, p2};
#pragma unroll
    for (int p = 0; p < NP; ++p) {
        const float* Ag = ps[p].Aptr; const float* Wg = ps[p].Wptr;
        const int lda = ps[p].lda, ldw = ps[p].ldw, K = ps[p].K;
        for (int k0 = 0; k0 < K; k0 += 16) {
            {
                const int k = tid & 15, mb = tid >> 4;
#pragma unroll
                for (int i = 0; i < 4; ++i) {
                    const int m = mb + 16 * i, gr = row0 + m;
                    float v = 0.f;
                    if (gr < M) v = Ag[(size_t)gr * lda + k0 + k];
                    As[m][k] = v;
                }
            }
            {
                const int n = tid & 63, kb = tid >> 6, gc = col0 + n;
#pragma unroll
                for (int i = 0; i < 4; ++i) {
                    const int k = kb * 4 + i;
                    float v = 0.f;
                    if (gc < N) v = Wg[(size_t)(k0 + k) * ldw + gc];
                    Ws[k][n] = v;
                }
            }
            __syncthreads();
#pragma unroll
            for (int k = 0; k < 16; ++k) {
                float av[4];
#pragma unroll
                for (int i = 0; i < 4; ++i) av[i] = As[ty * 4 + i][k];
                const float4 bv = reinterpret_cast<const float4*>(&Ws[k][0])[tx];
                const float bvv[4] = {bv.x, bv.y, bv.z, bv.w};
#pragma unroll
                for (int i = 0; i < 4; ++i)
#pragma unroll
                    for (int j = 0; j < 4; ++j) acc[i][j] += av[i] * bvv[j];
            }
            __syncthreads();
        }
    }
#pragma unroll
    for (int i = 0; i < 4; ++i) {
        const int r = row0 + ty * 4 + i;
        if (r >= M) continue;
#pragma unroll
        for (int j = 0; j < 4; ++j) {
            const int cidx = col0 + tx * 4 + j;
            if (cidx >= N) continue;
            float v = acc[i][j];
            if (bias1) v += bias1[cidx];
            if (bias2) v += bias2[cidx];
            C[(size_t)r * ldc + cidx] = v;
        }
    }
}

__global__ __launch_bounds__(256) void mean_pool(const float* __restrict__ F,
                                                 float* __restrict__ mean)
{
    const int idx = blockIdx.x * 256 + threadIdx.x;
    const int b = idx >> 11, e = idx & (E - 1);
    const float* Fb = F + (size_t)b * S * E + e;
    float acc = 0.f;
    for (int s = 0; s < S; ++s) acc += Fb[(size_t)s * E];
    mean[idx] = acc * (1.f / (float)S);
}

__global__ __launch_bounds__(256) void gather_embs(const int* __restrict__ captions,
                                                   const float* __restrict__ table,
                                                   float* __restrict__ out)
{
    const int idx = blockIdx.x * 256 + threadIdx.x;
    const int per_row = EM / 4;
    const int row = idx / per_row;
    const int col = idx - row * per_row;
    const int cap = captions[row];
    reinterpret_cast<float4*>(out)[idx] =
        reinterpret_cast<const float4*>(table + (size_t)cap * EM)[col];
}

__global__ __launch_bounds__(256) void attn_softmax(
    const float* __restrict__ enc_att, const float* __restrict__ dec_att,
    const float* __restrict__ W_fa, const float* __restrict__ b_fa,
    float* __restrict__ alpha)
{
    const int b = blockIdx.x, tid = threadIdx.x;
    const int wave = tid >> 6, lane = tid & 63;
    __shared__ float dec[A], wfa[A], sc[S], redm[4], reds[4];
    dec[tid] = dec_att[b * A + tid];
    wfa[tid] = W_fa[tid];
    __syncthreads();
    for (int s = wave; s < S; s += 4) {
        const float* ea = enc_att + ((size_t)b * S + s) * A;
        float v = 0.f;
#pragma unroll
        for (int i = 0; i < 4; ++i) {
            const int a = lane + 64 * i;
            float x = ea[a] + dec[a];
            x = x > 0.f ? x : 0.f;
            v += x * wfa[a];
        }
        for (int off = 32; off; off >>= 1) v += __shfl_down(v, off);
        if (lane == 0) sc[s] = v + b_fa[0];
    }
    __syncthreads();
    float m = -1e30f;
    for (int s = tid; s < S; s += 256) m = fmaxf(m, sc[s]);
    for (int off = 32; off; off >>= 1) m = fmaxf(m, __shfl_down(m, off));
    if (lane == 0) redm[wave] = m;
    __syncthreads();
    if (tid == 0) redm[0] = fmaxf(fmaxf(redm[0], redm[1]), fmaxf(redm[2], redm[3]));
    __syncthreads();
    m = redm[0];
    float sum = 0.f;
    for (int s = tid; s < S; s += 256) {
        const float ev = expf(sc[s] - m);
        sc[s] = ev; sum += ev;
    }
    for (int off = 32; off; off >>= 1) sum += __shfl_down(sum, off);
    if (lane == 0) reds[wave] = sum;
    __syncthreads();
    if (tid == 0) reds[0] = reds[0] + reds[1] + reds[2] + reds[3];
    __syncthreads();
    const float inv = 1.f / reds[0];
    for (int s = tid; s < S; s += 256) alpha[b * S + s] = sc[s] * inv;
}

__global__ __launch_bounds__(256) void context_kernel(
    const float* __restrict__ F, const float* __restrict__ alpha,
    float* __restrict__ ctx)
{
    const int chunks = E / 256;
    const int b = blockIdx.x / chunks;
    const int ec = blockIdx.x - b * chunks;
    const int e = ec * 256 + threadIdx.x;
    __shared__ float al[S];
    for (int s = threadIdx.x; s < S; s += 256) al[s] = alpha[b * S + s];
    __syncthreads();
    const float* Fb = F + (size_t)b * S * E + e;
    float acc = 0.f;
    for (int s = 0; s < S; ++s) acc += al[s] * Fb[(size_t)s * E];
    ctx[b * E + e] = acc;
}

__global__ __launch_bounds__(256) void lstm_cell(
    const float* __restrict__ gates, float* __restrict__ h, float* __restrict__ c)
{
    const int idx = blockIdx.x * 256 + threadIdx.x;
    const int b = idx >> 9, d = idx & (D - 1);
    const float* g = gates + (size_t)b * 4 * D;
    const float gi = g[d], gf = g[D + d], gg = g[2 * D + d], go = g[3 * D + d];
    const float cn = sigm(gf) * c[idx] + sigm(gi) * tanhf(gg);
    c[idx] = cn;
    h[idx] = sigm(go) * tanhf(cn);
}

// ===========================================================================
// launch
// ===========================================================================
extern "C" void kernel_launch(void* const* d_in, const int* in_sizes, int n_in,
                              void* d_out, int out_size, void* d_ws, size_t ws_size,
                              hipStream_t stream)
{
    const float* F        = (const float*)d_in[0];
    const int*   captions = (const int*)  d_in[1];
    const float* table    = (const float*)d_in[2];
    const float* W_ea     = (const float*)d_in[3];
    const float* b_ea     = (const float*)d_in[4];
    const float* W_da     = (const float*)d_in[5];
    const float* b_da     = (const float*)d_in[6];
    const float* W_fa     = (const float*)d_in[7];
    const float* b_fa     = (const float*)d_in[8];
    const float* W_ih     = (const float*)d_in[9];
    const float* b_ih     = (const float*)d_in[10];
    const float* W_hh     = (const float*)d_in[11];
    const float* b_hh     = (const float*)d_in[12];
    const float* W_cp     = (const float*)d_in[13];
    const float* b_cp     = (const float*)d_in[14];
    const float* W_hp     = (const float*)d_in[15];
    const float* b_hp     = (const float*)d_in[16];
    const float* W_op     = (const float*)d_in[17];
    const float* b_op     = (const float*)d_in[18];
    const float* W_inith  = (const float*)d_in[19];
    const float* b_inith  = (const float*)d_in[20];
    const float* W_initc  = (const float*)d_in[21];
    const float* b_initc  = (const float*)d_in[22];

    float* out = (float*)d_out;
    const int VP2 = 10240;  // V padded to 128-span

    // ---- workspace allocator (256 B aligned) ----
    char* base = (char*)d_ws;
    size_t off = 0;
    auto alloc = [&](size_t bytes) -> void* {
        off = (off + 255) & ~(size_t)255;
        void* p = base + off;
        off += bytes;
        return p;
    };

    u16* W_eaT    = (u16*)alloc((size_t)A * E * 2);
    u16* W_daT    = (u16*)alloc((size_t)A * D * 2);
    u16* W_ihT    = (u16*)alloc((size_t)(4 * D) * (EM + E) * 2);  // gate-interleaved
    u16* W_hhT    = (u16*)alloc((size_t)(4 * D) * D * 2);         // gate-interleaved
    u16* W_cpT    = (u16*)alloc((size_t)EM * E * 2);
    u16* W_hpT    = (u16*)alloc((size_t)EM * D * 2);
    u16* W_opT    = (u16*)alloc((size_t)VP2 * EM * 2);
    u16* W_inithT = (u16*)alloc((size_t)D * E * 2);
    u16* W_initcT = (u16*)alloc((size_t)D * E * 2);
    u16* embs     = (u16*)alloc((size_t)B * T * EM * 2);
    u16* mean_bf  = (u16*)alloc((size_t)B * E * 2);
    u16* h_cur    = (u16*)alloc((size_t)B * D * 2);
    u16* h_all    = (u16*)alloc((size_t)B * T * D * 2);
    u16* ctx_all  = (u16*)alloc((size_t)B * T * E * 2);
    u16* feat_all = (u16*)alloc((size_t)B * T * EM * 2);
    u16* enc_bf   = (u16*)alloc((size_t)B * S * A * 2);
    float* c_st   = (float*)alloc((size_t)B * D * 4);
    float* alpha  = (float*)alloc((size_t)B * S * 4);
    float* part   = (float*)alloc((size_t)4 * B * 2048 * 4);
    const size_t need_base = off;
    u16* F_bf     = (u16*)alloc((size_t)B * S * E * 2);
    const size_t need_fbf = off;

    const bool ok_base = need_base <= ws_size;
    const bool ok_fbf  = need_fbf <= ws_size;

    if (!ok_base) {
        // ---------------- fp32 fallback ----------------
        float* ws = (float*)d_ws;
        float* mean_feat = ws;  ws += B * E;
        float* h         = ws;  ws += B * D;
        float* c         = ws;  ws += B * D;
        float* enc_att   = ws;  ws += (size_t)B * S * A;
        float* fembs     = ws;  ws += (size_t)B * T * EM;
        float* fdec      = ws;  ws += B * A;
        float* falpha    = ws;  ws += B * S;
        float* fctx      = ws;  ws += B * E;
        float* fgates    = ws;  ws += B * 4 * D;
        float* ffeat     = ws;  ws += B * EM;
        const Pair ZP = {nullptr, 0, nullptr, 0, 0};
        mean_pool<<<(B * E) / 256, 256, 0, stream>>>(F, mean_feat);
        { Pair p = {mean_feat, E, W_inith, D, E};
          gemm_f32<1><<<dim3(D / 64, B / 64), 256, 0, stream>>>(B, D, p, ZP, ZP, b_inith, nullptr, h, D); }
        { Pair p = {mean_feat, E, W_initc, D, E};
          gemm_f32<1><<<dim3(D / 64, B / 64), 256, 0, stream>>>(B, D, p, ZP, ZP, b_initc, nullptr, c, D); }
        { Pair p = {F, E, W_ea, A, E};
          gemm_f32<1><<<dim3(A / 64, (B * S) / 64), 256, 0, stream>>>(B * S, A, p, ZP, ZP, b_ea, nullptr, enc_att, A); }
        gather_embs<<<(B * T * (EM / 4)) / 256, 256, 0, stream>>>(captions, table, fembs);
        for (int t = 0; t < T; ++t) {
            { Pair p = {h, D, W_da, A, D};
              gemm_f32<1><<<dim3(A / 64, B / 64), 256, 0, stream>>>(B, A, p, ZP, ZP, b_da, nullptr, fdec, A); }
            attn_softmax<<<B, 256, 0, stream>>>(enc_att, fdec, W_fa, b_fa, falpha);
            context_kernel<<<B * (E / 256), 256, 0, stream>>>(F, falpha, fctx);
            { Pair p0 = {fembs + (size_t)t * EM, T * EM, W_ih, 4 * D, EM};
              Pair p1 = {fctx, E, W_ih + (size_t)EM * 4 * D, 4 * D, E};
              Pair p2 = {h, D, W_hh, 4 * D, D};
              gemm_f32<3><<<dim3((4 * D) / 64, B / 64), 256, 0, stream>>>(B, 4 * D, p0, p1, p2, b_ih, b_hh, fgates, 4 * D); }
            lstm_cell<<<(B * D) / 256, 256, 0, stream>>>(fgates, h, c);
            { Pair p0 = {fctx, E, W_cp, EM, E};
              Pair p1 = {h, D, W_hp, EM, D};
              gemm_f32<2><<<dim3(EM / 64, B / 64), 256, 0, stream>>>(B, EM, p0, p1, ZP, b_cp, b_hp, ffeat, EM); }
            { Pair p = {ffeat, EM, W_op, V, EM};
              gemm_f32<1><<<dim3((V + 63) / 64, B / 64), 256, 0, stream>>>(B, V, p, ZP, ZP, b_op, nullptr, out + (size_t)t * V, (long)T * V); }
        }
        return;
    }

    // ---------------- bf16 MFMA path ----------------
    const PairT ZP = {nullptr, 0, nullptr, 0, 0};

    // weight transposes
    transpose_bf<<<dim3(A / 32, E / 32), 256, 0, stream>>>(W_ea, E, A, W_eaT);
    transpose_bf<<<dim3(A / 32, D / 32), 256, 0, stream>>>(W_da, D, A, W_daT);
    transpose_bf_gates<<<dim3((4 * D) / 32, (EM + E) / 32), 256, 0, stream>>>(W_ih, EM + E, W_ihT);
    transpose_bf_gates<<<dim3((4 * D) / 32, D / 32), 256, 0, stream>>>(W_hh, D, W_hhT);
    transpose_bf<<<dim3(EM / 32, E / 32), 256, 0, stream>>>(W_cp, E, EM, W_cpT);
    transpose_bf<<<dim3(EM / 32, D / 32), 256, 0, stream>>>(W_hp, D, EM, W_hpT);
    transpose_bf<<<dim3(VP2 / 32, EM / 32), 256, 0, stream>>>(W_op, EM, V, W_opT);
    transpose_bf<<<dim3(D / 32, E / 32), 256, 0, stream>>>(W_inith, E, D, W_inithT);
    transpose_bf<<<dim3(D / 32, E / 32), 256, 0, stream>>>(W_initc, E, D, W_initcT);

    if (ok_fbf)
        conv_mean<true><<<(B * E) / 256, 256, 0, stream>>>(F, F_bf, mean_bf);
    else
        conv_mean<false><<<(B * E) / 256, 256, 0, stream>>>(F, nullptr, mean_bf);

    gather_embs_bf<<<(B * T * (EM / 8)) / 256, 256, 0, stream>>>(captions, table, embs);

    // h0 (bf16), c0 (fp32)
    { PairT p = {mean_bf, E, W_inithT, E, E};
      gemm_mfma<1, false, u16, 2, 4, 1, 4><<<dim3(2, 4), 256, 0, stream>>>(
          D, p, ZP, ZP, b_inith, nullptr, h_cur, D); }
    { PairT p = {mean_bf, E, W_initcT, E, E};
      gemm_mfma<1, false, float, 2, 4, 1, 4><<<dim3(2, 4), 256, 0, stream>>>(
          D, p, ZP, ZP, b_initc, nullptr, c_st, D); }

    // enc_att: wave 32x64, block 64M x 128N, grid (2, 392) = 784 blocks
    if (ok_fbf) {
        PairT p = {F_bf, E, W_eaT, E, E};
        gemm_mfma<1, false, u16, 2, 4, 2, 2><<<dim3(2, (B * S) / 64), 256, 0, stream>>>(
            A, p, ZP, ZP, b_ea, nullptr, enc_bf, A);
    } else {
        PairT p = {F, E, W_eaT, E, E};
        gemm_mfma<1, true, u16, 2, 4, 2, 2><<<dim3(2, (B * S) / 64), 256, 0, stream>>>(
            A, p, ZP, ZP, b_ea, nullptr, enc_bf, A);
    }

    // ---- per-step loop: 4 kernels/step ----
    for (int t = 0; t < T; ++t) {
        attn_alpha<<<B, 256, 0, stream>>>(enc_bf, h_cur, W_daT, b_da, W_fa, b_fa, alpha);

        if (ok_fbf)
            context_wide<true><<<B * 2, 256, 0, stream>>>(F_bf, alpha, ctx_all, t);
        else
            context_wide<false><<<B * 2, 256, 0, stream>>>(F, alpha, ctx_all, t);

        { // split-K gates: z0 = emb(K=512), z1/z2 = ctx halves (K=1024 each), z3 = h(K=512)
          PairT q0 = {embs + (size_t)t * EM, (long)T * EM, W_ihT, EM + E, EM};
          PairT q1 = {ctx_all + (size_t)t * E, (long)T * E, W_ihT + EM, EM + E, 1024};
          PairT q2 = {ctx_all + (size_t)t * E + 1024, (long)T * E, W_ihT + EM + 1024, EM + E, 1024};
          PairT q3 = {h_cur, D, W_hhT, D, D};
          gates_split<<<dim3(16, 8, 4), 128, 0, stream>>>(q0, q1, q2, q3, part); }

        lstm_finish<<<(B * D) / 256, 256, 0, stream>>>(
            part, b_ih, b_hh, c_st, h_cur, h_all, t);
    }

    // ---- batched tail: feat for all (b,t), then logits ----
    { PairT p0 = {ctx_all, E, W_cpT, E, E};
      PairT p1 = {h_all, D, W_hpT, D, D};
      gemm_mfma<2, false, u16, 1, 4, 2, 2><<<dim3(EM / 128, (B * T) / 32), 256, 0, stream>>>(
          EM, p0, p1, ZP, b_cp, b_hp, feat_all, EM); }

    { PairT p = {feat_all, EM, W_opT, EM, EM};
      gemm_mfma<1, false, float, 4, 4, 2, 2><<<dim3(VP2 / 128, (B * T) / 128), 256, 0, stream>>>(
          V, p, ZP, ZP, b_op, nullptr, out, V); }
}